// Round 7
// baseline (376.197 us; speedup 1.0000x reference)
//
#include <hip/hip_runtime.h>
#include <hip/hip_fp16.h>
#include <math.h>

// 2-layer GAT. N=50000, E=800000 (+N self loops), F=128, H=8, C=32, NCLS=16.
// R7: agg1 restructured for L2 locality. h1/h2 stored HEAD-MAJOR
// (h1h[head][node][32ch], 3.2MB/head -- fits one XCD's 4MB L2). agg1 task =
// (dst,head) pair; blockIdx%8 = head pins each head's blocks to one XCD
// (round-robin dispatch heuristic) so gathers hit a resident slice.
// Predicted: agg1 FETCH 221MB -> ~80MB, 70us -> ~30us.
// Also: 8 lanes/edge x 8 edge-groups x2 unroll = 16 edges in flight per wave.
// CSR build and gemm1 unchanged from R6; gemm2 A-load re-indexed for head-major.

#define NB    64
#define NBINS 50000
#define NW    25000

typedef _Float16 f16x8 __attribute__((ext_vector_type(8)));
typedef _Float16 f16x4 __attribute__((ext_vector_type(4)));
typedef float    f32x4 __attribute__((ext_vector_type(4)));

__device__ __forceinline__ float lrelu(float v){ return v > 0.f ? v : 0.2f*v; }

// ---------------- hist (packed u16) + weight prep ----------------
__global__ __launch_bounds__(256) void k_histW(const int* __restrict__ dstv,
    unsigned int* __restrict__ partial, int E, int Etot, int chunk,
    const float* __restrict__ W1, _Float16* __restrict__ W1t,
    const float* __restrict__ W2, _Float16* __restrict__ W2t)
{
  int b = blockIdx.x, t = threadIdx.x;
  if (b >= NB){
    int b2 = b - NB;
    if (b2 < 128){
      W1t[t*128 + b2] = (_Float16)W1[b2*256 + t];
    } else {
      for (int i=t; i<4096; i+=256){ int k=i&255, j=i>>8; W2t[j*256+k] = (_Float16)W2[k*16+j]; }
    }
    return;
  }
  __shared__ unsigned int cnt[NW];
  for (int i=t; i<NW; i+=256) cnt[i] = 0u;
  __syncthreads();
  int e0 = b*chunk, e1 = e0+chunk; if (e1 > Etot) e1 = Etot;
  int e = e0 + t;
  for (; e + 768 < e1; e += 1024){
    int ea=e, eb=e+256, ec=e+512, ed=e+768;
    int d0 = (ea<E)?dstv[ea]:(ea-E);
    int d1 = (eb<E)?dstv[eb]:(eb-E);
    int d2 = (ec<E)?dstv[ec]:(ec-E);
    int d3 = (ed<E)?dstv[ed]:(ed-E);
    atomicAdd(&cnt[d0>>1], (d0&1)?65536u:1u);
    atomicAdd(&cnt[d1>>1], (d1&1)?65536u:1u);
    atomicAdd(&cnt[d2>>1], (d2&1)?65536u:1u);
    atomicAdd(&cnt[d3>>1], (d3&1)?65536u:1u);
  }
  for (; e < e1; e += 256){
    int d = (e<E)?dstv[e]:(e-E);
    atomicAdd(&cnt[d>>1], (d&1)?65536u:1u);
  }
  __syncthreads();
  unsigned int* dp = partial + (size_t)b*NW;
  for (int i=t; i<NW; i+=256) dp[i] = cnt[i];
}

// ---------------- scanA + scan1 fused ----------------
__global__ __launch_bounds__(256) void k_scanAB(unsigned long long* __restrict__ partial,
    int* __restrict__ rowptr, int* __restrict__ bsum, int N)
{
  __shared__ int lds[256];
  int t = threadIdx.x, blk = blockIdx.x;
  int base = blk*1024 + t*4;
  int r0=0, r1=0, r2=0, r3=0;
  if (base < N){
    unsigned long long* P = partial + (base >> 2);
    #pragma unroll 8
    for (int b=0; b<NB; ++b){
      unsigned long long v = P[(size_t)b*12500];
      unsigned long long pref =  (unsigned long long)(r0 & 0xffff)
        | ((unsigned long long)(r1 & 0xffff) << 16)
        | ((unsigned long long)(r2 & 0xffff) << 32)
        | ((unsigned long long)(r3 & 0xffff) << 48);
      P[(size_t)b*12500] = pref;
      r0 += (int)( v        & 0xffff);
      r1 += (int)((v >> 16) & 0xffff);
      r2 += (int)((v >> 32) & 0xffff);
      r3 += (int)((v >> 48) & 0xffff);
    }
  }
  int tot = r0+r1+r2+r3;
  lds[t] = tot; __syncthreads();
  for (int off=1; off<256; off<<=1){
    int add = (t>=off)?lds[t-off]:0;
    __syncthreads();
    lds[t] += add;
    __syncthreads();
  }
  int excl = lds[t] - tot;
  if (t==255) bsum[blk] = lds[t];
  int run = excl;
  if (base+0<N){ rowptr[base+0]=run; run+=r0; }
  if (base+1<N){ rowptr[base+1]=run; run+=r1; }
  if (base+2<N){ rowptr[base+2]=run; run+=r2; }
  if (base+3<N){ rowptr[base+3]=run; }
}

// ---------------- scatter (fuses scan2+scan3 redundantly per block) ----------------
__global__ __launch_bounds__(256) void k_scatter3(const int* __restrict__ srcv,
    const int* __restrict__ dstv, const int* __restrict__ rowptr,
    const unsigned short* __restrict__ pu, const int* __restrict__ bsum,
    int* __restrict__ csr_src, int E, int Etot, int chunk, int SB)
{
  __shared__ unsigned int cur[NW];
  __shared__ int bpre[64];
  int b = blockIdx.x, t = threadIdx.x;
  for (int i=t; i<NW; i+=256) cur[i] = 0u;
  if (t==0){ int run=0; for (int j=0;j<SB;++j){ bpre[j]=run; run+=bsum[j]; } }
  __syncthreads();
  const unsigned short* pb = pu + (size_t)b*NBINS;
  int e0 = b*chunk, e1 = e0+chunk; if (e1 > Etot) e1 = Etot;
  int e = e0 + t;
  for (; e + 768 < e1; e += 1024){
    int ea=e, eb=e+256, ec=e+512, ed=e+768;
    int d0,s0,d1,s1,d2,s2,d3,s3;
    if (ea<E){ d0=dstv[ea]; s0=srcv[ea]; } else { d0=ea-E; s0=d0; }
    if (eb<E){ d1=dstv[eb]; s1=srcv[eb]; } else { d1=eb-E; s1=d1; }
    if (ec<E){ d2=dstv[ec]; s2=srcv[ec]; } else { d2=ec-E; s2=d2; }
    if (ed<E){ d3=dstv[ed]; s3=srcv[ed]; } else { d3=ed-E; s3=d3; }
    int base0 = rowptr[d0] + bpre[d0>>10] + (int)pb[d0];
    int base1 = rowptr[d1] + bpre[d1>>10] + (int)pb[d1];
    int base2 = rowptr[d2] + bpre[d2>>10] + (int)pb[d2];
    int base3 = rowptr[d3] + bpre[d3>>10] + (int)pb[d3];
    unsigned int o0 = atomicAdd(&cur[d0>>1], (d0&1)?65536u:1u);
    csr_src[base0 + ((d0&1)?(int)(o0>>16):(int)(o0&0xffff))] = s0;
    unsigned int o1 = atomicAdd(&cur[d1>>1], (d1&1)?65536u:1u);
    csr_src[base1 + ((d1&1)?(int)(o1>>16):(int)(o1&0xffff))] = s1;
    unsigned int o2 = atomicAdd(&cur[d2>>1], (d2&1)?65536u:1u);
    csr_src[base2 + ((d2&1)?(int)(o2>>16):(int)(o2&0xffff))] = s2;
    unsigned int o3 = atomicAdd(&cur[d3>>1], (d3&1)?65536u:1u);
    csr_src[base3 + ((d3&1)?(int)(o3>>16):(int)(o3&0xffff))] = s3;
  }
  for (; e < e1; e += 256){
    int d,s;
    if (e<E){ d=dstv[e]; s=srcv[e]; } else { d=e-E; s=d; }
    int base = rowptr[d] + bpre[d>>10] + (int)pb[d];
    unsigned int o = atomicAdd(&cur[d>>1], (d&1)?65536u:1u);
    csr_src[base + ((d&1)?(int)(o>>16):(int)(o&0xffff))] = s;
  }
}

// ---------------- GEMM1 (MFMA) + rowptr finalize; h1 stored HEAD-MAJOR ----------------
__global__ __launch_bounds__(256) void k_gemm1(const float* __restrict__ x,
    const _Float16* __restrict__ W1t, const float* __restrict__ as1,
    const float* __restrict__ ad1, _Float16* __restrict__ h1h,
    float* __restrict__ a_src1, float* __restrict__ a_dst1,
    int* __restrict__ rowptr, const int* __restrict__ bsum, int SB, int Etot, int N)
{
  __shared__ char smem[33792];
  _Float16* As = (_Float16*)smem;           // [64 rows][136 halves] (272 B stride)
  int t = threadIdx.x;
  int n0 = blockIdx.x*64;

  if ((int)blockIdx.x < SB){
    int blk = blockIdx.x;
    int pref = 0;
    for (int j=0;j<blk;++j) pref += bsum[j];
    int i = blk*1024 + t*4;
    if (i+0 < N) rowptr[i+0] += pref;
    if (i+1 < N) rowptr[i+1] += pref;
    if (i+2 < N) rowptr[i+2] += pref;
    if (i+3 < N) rowptr[i+3] += pref;
    if (blk==0 && t==0) rowptr[N] = Etot;
  }

  #pragma unroll
  for (int it=0; it<8; ++it){
    int c = it*256 + t;
    int row = c >> 5;
    int c4  = c & 31;
    int gr = n0 + row; if (gr > N-1) gr = N-1;
    float4 v = *(const float4*)(x + (size_t)gr*128 + c4*4);
    _Float16* dp = As + row*136 + c4*4;
    dp[0]=(_Float16)v.x; dp[1]=(_Float16)v.y; dp[2]=(_Float16)v.z; dp[3]=(_Float16)v.w;
  }
  __syncthreads();

  int wv = t>>6, lane = t&63;
  int m = lane&15, q = lane>>4;
  int r0w = wv*16;

  f16x8 afr[4];
  #pragma unroll
  for (int ks=0; ks<4; ++ks)
    afr[ks] = *(const f16x8*)((const char*)As + (r0w+m)*272 + ks*64 + q*16);

  f32x4 acc[16];
  #pragma unroll
  for (int ct=0; ct<16; ++ct) acc[ct] = (f32x4){0.f,0.f,0.f,0.f};

  const char* bbase = (const char*)W1t;
  #pragma unroll
  for (int ct=0; ct<16; ++ct){
    const char* bp = bbase + (ct*16 + m)*256 + q*16;
    f16x8 b0 = *(const f16x8*)(bp);
    f16x8 b1 = *(const f16x8*)(bp+64);
    f16x8 b2 = *(const f16x8*)(bp+128);
    f16x8 b3 = *(const f16x8*)(bp+192);
    acc[ct] = __builtin_amdgcn_mfma_f32_16x16x32_f16(afr[0], b0, acc[ct],0,0,0);
    acc[ct] = __builtin_amdgcn_mfma_f32_16x16x32_f16(afr[1], b1, acc[ct],0,0,0);
    acc[ct] = __builtin_amdgcn_mfma_f32_16x16x32_f16(afr[2], b2, acc[ct],0,0,0);
    acc[ct] = __builtin_amdgcn_mfma_f32_16x16x32_f16(afr[3], b3, acc[ct],0,0,0);
  }
  __syncthreads();

  _Float16* Hs = (_Float16*)smem;           // [64][264] halves, 528B stride
  #pragma unroll
  for (int ct=0; ct<16; ++ct){
    #pragma unroll
    for (int r=0; r<4; ++r)
      Hs[(size_t)(r0w + q*4 + r)*264 + ct*16 + m] = (_Float16)acc[ct][r];
  }
  __syncthreads();

  // h1 store HEAD-MAJOR: lane = head*8 + chunk; per row 8 heads x 64B
  {
    int hd = lane >> 3, cl = lane & 7;
    for (int r=0; r<16; ++r){
      int grow = n0 + r0w + r;
      if (grow < N){
        uint2 v = *(const uint2*)((const char*)Hs + (size_t)(r0w+r)*528 + hd*64 + cl*8);
        *(uint2*)((char*)h1h + ((size_t)hd*N + grow)*64 + cl*8) = v;
      }
    }
  }

  #pragma unroll
  for (int p=t; p<512; p+=256){
    int row = p>>3, hd = p&7;
    int grow = n0 + row;
    if (grow < N){
      const _Float16* hr = Hs + (size_t)row*264 + hd*32;
      float sa=0.f, sd=0.f;
      #pragma unroll
      for (int c=0; c<32; ++c){
        float hv = (float)hr[c];
        sa += hv * as1[hd*32+c];
        sd += hv * ad1[hd*32+c];
      }
      a_src1[(size_t)grow*8+hd] = sa;
      a_dst1[(size_t)grow*8+hd] = sd;
    }
  }
}

// ---------------- Layer-1 aggregation: wave per (dst,head); blockIdx%8=head (XCD pin) ----------------
__global__ __launch_bounds__(256) void k_agg1(const __half* __restrict__ h1h,
    const float* __restrict__ a_src1, const float* __restrict__ a_dst1,
    const int* __restrict__ rowptr, const int* __restrict__ csr_src,
    const float* __restrict__ bias1, _Float16* __restrict__ h2h, int N)
{
  int h  = blockIdx.x & 7;
  int wv = threadIdx.x >> 6;
  int dst = (blockIdx.x >> 3)*4 + wv;
  if (dst >= N) return;
  int lane = threadIdx.x & 63;
  int eg = lane >> 3, cl = lane & 7;       // 8 edge groups x 8B chunks
  float ad = a_dst1[(size_t)dst*8 + h];
  int beg = rowptr[dst], end = rowptr[dst+1];
  const char* hbase = (const char*)h1h + (size_t)h*N*64 + cl*8;
  float4 acc = make_float4(0.f,0.f,0.f,0.f);
  float wsum = 0.f;
  int i = beg + eg;
  for (; i + 8 < end; i += 16){
    int s0 = csr_src[i], s1 = csr_src[i+8];
    float e0 = a_src1[(size_t)s0*8 + h];
    float e1 = a_src1[(size_t)s1*8 + h];
    uint2 p0 = *(const uint2*)(hbase + (size_t)s0*64);
    uint2 p1 = *(const uint2*)(hbase + (size_t)s1*64);
    float w0 = __expf(lrelu(e0+ad)), w1 = __expf(lrelu(e1+ad));
    wsum += w0 + w1;
    const __half2* q0=(const __half2*)&p0; const __half2* q1=(const __half2*)&p1;
    float2 a0=__half22float2(q0[0]), b0=__half22float2(q0[1]);
    float2 a1=__half22float2(q1[0]), b1=__half22float2(q1[1]);
    acc.x += w0*a0.x + w1*a1.x;
    acc.y += w0*a0.y + w1*a1.y;
    acc.z += w0*b0.x + w1*b1.x;
    acc.w += w0*b0.y + w1*b1.y;
  }
  for (; i < end; i += 8){
    int s = csr_src[i];
    float w = __expf(lrelu(a_src1[(size_t)s*8 + h] + ad));
    wsum += w;
    uint2 p = *(const uint2*)(hbase + (size_t)s*64);
    const __half2* qq=(const __half2*)&p;
    float2 f0=__half22float2(qq[0]), f1=__half22float2(qq[1]);
    acc.x += w*f0.x; acc.y += w*f0.y; acc.z += w*f1.x; acc.w += w*f1.y;
  }
  // reduce across edge groups (lane bits 3..5)
  #pragma unroll
  for (int msk=8; msk<=32; msk<<=1){
    acc.x += __shfl_xor(acc.x, msk);
    acc.y += __shfl_xor(acc.y, msk);
    acc.z += __shfl_xor(acc.z, msk);
    acc.w += __shfl_xor(acc.w, msk);
    wsum  += __shfl_xor(wsum,  msk);
  }
  if (eg == 0){
    float dinv = 1.f/(wsum + 1e-16f);
    const float4 bv = *(const float4*)(bias1 + h*32 + cl*4);
    float4 o;
    o.x = acc.x*dinv + bv.x;
    o.y = acc.y*dinv + bv.y;
    o.z = acc.z*dinv + bv.z;
    o.w = acc.w*dinv + bv.w;
    o.x = o.x > 0.f ? o.x : __expf(o.x)-1.f;
    o.y = o.y > 0.f ? o.y : __expf(o.y)-1.f;
    o.z = o.z > 0.f ? o.z : __expf(o.z)-1.f;
    o.w = o.w > 0.f ? o.w : __expf(o.w)-1.f;
    f16x4 ov = { (_Float16)o.x, (_Float16)o.y, (_Float16)o.z, (_Float16)o.w };
    *(f16x4*)((char*)h2h + ((size_t)h*N + dst)*64 + cl*8) = ov;
  }
}

// ---------------- GEMM2 (MFMA): hb = h2 @ W2, h2 HEAD-MAJOR ----------------
__global__ __launch_bounds__(256) void k_gemm2(const _Float16* __restrict__ h2h,
    const _Float16* __restrict__ W2t, const float* __restrict__ as2, const float* __restrict__ ad2,
    float* __restrict__ hb, float* __restrict__ a_src2, float* __restrict__ a_dst2, int N)
{
  int t = threadIdx.x, wv = t>>6, lane = t&63;
  int col = lane&15, q = lane>>4;
  int n0 = blockIdx.x*64 + wv*16;
  int am = n0 + col; if (am > N-1) am = N-1;

  const _Float16* brow = W2t + (size_t)col*256 + q*8;
  f32x4 acc = (f32x4){0.f,0.f,0.f,0.f};
  #pragma unroll
  for (int ks=0; ks<8; ++ks){
    // k = ks*32 + q*8 + j : head = ks, ch = q*8+j  (head-major h2)
    f16x8 a = *(const f16x8*)(h2h + ((size_t)ks*N + am)*32 + q*8);
    f16x8 b = *(const f16x8*)(brow + ks*32);
    acc = __builtin_amdgcn_mfma_f32_16x16x32_f16(a, b, acc, 0,0,0);
  }

  float vs = as2[col], vd = ad2[col];
  #pragma unroll
  for (int r=0; r<4; ++r){
    int n = n0 + q*4 + r;
    float v = acc[r];
    float pa = v*vs, pd = v*vd;
    #pragma unroll
    for (int msk=8; msk>=1; msk>>=1){ pa += __shfl_xor(pa,msk); pd += __shfl_xor(pd,msk); }
    if (n < N){
      hb[(size_t)n*16 + col] = v;
      if (col==0){ a_src2[n] = pa; a_dst2[n] = pd; }
    }
  }
}

// ---------------- Layer-2 aggregation: wave per dst, 4 edge-groups x 16 ch ----------------
__global__ __launch_bounds__(256) void k_agg2(const float* __restrict__ hb,
    const float* __restrict__ a_src2, const float* __restrict__ a_dst2,
    const int* __restrict__ rowptr, const int* __restrict__ csr_src,
    const float* __restrict__ bias2, float* __restrict__ out, int N)
{
  int wave = (blockIdx.x*blockDim.x + threadIdx.x) >> 6;
  if (wave >= N) return;
  int lane = threadIdx.x & 63;
  int eg   = lane >> 4;
  int ch   = lane & 15;
  float ad = a_dst2[wave];
  int beg = rowptr[wave], end = rowptr[wave+1];
  float acc = 0.f, wsum = 0.f;
  int i = beg + eg;
  for (; i+4 < end; i+=8){
    int s0 = csr_src[i], s1 = csr_src[i+4];
    float e0 = a_src2[s0], e1 = a_src2[s1];
    float h0 = hb[(size_t)s0*16 + ch], h1v = hb[(size_t)s1*16 + ch];
    float w0 = __expf(lrelu(e0 + ad)), w1 = __expf(lrelu(e1 + ad));
    wsum += w0 + w1;
    acc += w0*h0 + w1*h1v;
  }
  for (; i<end; i+=4){
    int s = csr_src[i];
    float w = __expf(lrelu(a_src2[s] + ad));
    wsum += w;
    acc += w * hb[(size_t)s*16 + ch];
  }
  acc  += __shfl_xor(acc, 16);  acc  += __shfl_xor(acc, 32);
  wsum += __shfl_xor(wsum, 16); wsum += __shfl_xor(wsum, 32);
  if (eg == 0)
    out[(size_t)wave*16 + ch] = acc/(wsum + 1e-16f) + bias2[ch];
}

extern "C" void kernel_launch(void* const* d_in, const int* in_sizes, int n_in,
                              void* d_out, int out_size, void* d_ws, size_t ws_size,
                              hipStream_t stream)
{
  const float* x   = (const float*)d_in[0];
  const int*   ei  = (const int*)  d_in[1];
  const float* W1  = (const float*)d_in[2];
  const float* as1 = (const float*)d_in[3];
  const float* ad1 = (const float*)d_in[4];
  const float* b1  = (const float*)d_in[5];
  const float* W2  = (const float*)d_in[6];
  const float* as2 = (const float*)d_in[7];
  const float* ad2 = (const float*)d_in[8];
  const float* b2  = (const float*)d_in[9];
  float* out = (float*)d_out;

  const int N    = in_sizes[0] / 128;       // 50000
  const int E    = in_sizes[1] / 2;         // 800000
  const int Etot = E + N;
  const int* srcv = ei;
  const int* dstv = ei + E;
  const int chunk = (Etot + NB - 1) / NB;   // 13282 < 65536 (u16-field safe)
  const int SB    = (N + 1023) / 1024;      // 49 scan blocks

  char* p = (char*)d_ws;
  auto alloc = [&](size_t bytes)->void* {
    void* r = (void*)p;
    p += (bytes + 255) & ~((size_t)255);
    return r;
  };
  _Float16* h1h  = (_Float16*)alloc((size_t)N*256*sizeof(_Float16));   // head-major [8][N][32]
  _Float16* W1t  = (_Float16*)alloc((size_t)256*128*sizeof(_Float16));
  _Float16* h2h  = (_Float16*)alloc((size_t)N*256*sizeof(_Float16));   // head-major [8][N][32]
  _Float16* W2t  = (_Float16*)alloc((size_t)16*256*sizeof(_Float16));
  float* a_src1  = (float*)alloc((size_t)N*8*sizeof(float));
  float* a_dst1  = (float*)alloc((size_t)N*8*sizeof(float));
  float* hb      = (float*)alloc((size_t)N*16*sizeof(float));
  float* a_src2  = (float*)alloc((size_t)N*sizeof(float));
  float* a_dst2  = (float*)alloc((size_t)N*sizeof(float));
  int*   rowptr  = (int*)alloc((size_t)(N+1)*sizeof(int));
  int*   bsum    = (int*)alloc(256*sizeof(int));
  unsigned int* partial = (unsigned int*)alloc((size_t)NB*NW*sizeof(unsigned int));
  int*   csr_src = (int*)alloc((size_t)Etot*sizeof(int));

  // 1. histogram (packed u16) + weight prep
  k_histW<<<dim3(NB+129), dim3(256), 0, stream>>>(dstv, partial, E, Etot, chunk,
                                                  W1, W1t, W2, W2t);
  // 2. per-bin partial prefix + block-local rowptr + bsum
  k_scanAB<<<dim3(SB), dim3(256), 0, stream>>>((unsigned long long*)partial, rowptr, bsum, N);
  // 3. deterministic scatter
  k_scatter3<<<dim3(NB), dim3(256), 0, stream>>>(srcv, dstv, rowptr,
      (const unsigned short*)partial, bsum, csr_src, E, Etot, chunk, SB);
  // 4. GEMM1 (head-major h1; also finalizes rowptr)
  k_gemm1<<<dim3((N + 63)/64), dim3(256), 0, stream>>>(x, W1t, as1, ad1, h1h,
      a_src1, a_dst1, rowptr, bsum, SB, Etot, N);
  // 5. agg1: (dst,head) waves, blockIdx%8 = head for XCD pinning
  k_agg1<<<dim3(8*((N + 3)/4)), dim3(256), 0, stream>>>((const __half*)h1h, a_src1, a_dst1,
      rowptr, csr_src, b1, h2h, N);
  // 6-7. gemm2 (head-major A), agg2
  k_gemm2<<<dim3((N + 63)/64), dim3(256), 0, stream>>>(h2h, W2t, as2, ad2, hb, a_src2, a_dst2, N);
  k_agg2<<<dim3((N + 3)/4), dim3(256), 0, stream>>>(hb, a_src2, a_dst2, rowptr, csr_src, b2, out, N);
}

// Round 8
// 322.333 us; speedup vs baseline: 1.1671x; 1.1671x over previous
//
#include <hip/hip_runtime.h>
#include <hip/hip_fp16.h>
#include <math.h>

// 2-layer GAT. N=50000, E=800000 (+N self loops), F=128, H=8, C=32, NCLS=16.
// R8: R7's (dst,head) agg1 REVERTED (8x wave count -> per-wave overhead swamped
// the gather; 156us vs 70us). Back to R6 node-major h1, wave-per-dst, x8 unroll.
// NEW: gemm2 fused into agg1's epilogue -- the wave holds the full fp32 h2 row,
// stages it to LDS (seg-staggered vs bank conflicts) and computes
// hb = h2 @ W2 (+ a_src2/a_dst2) in-wave. Deletes the gemm2 kernel, its
// dispatch gap, and the 52MB h2 write+read.

#define NB    64
#define NBINS 50000
#define NW    25000

typedef _Float16 f16x8 __attribute__((ext_vector_type(8)));
typedef float    f32x4 __attribute__((ext_vector_type(4)));

__device__ __forceinline__ float lrelu(float v){ return v > 0.f ? v : 0.2f*v; }

// ---------------- hist (packed u16) + weight prep ----------------
__global__ __launch_bounds__(256) void k_histW(const int* __restrict__ dstv,
    unsigned int* __restrict__ partial, int E, int Etot, int chunk,
    const float* __restrict__ W1, _Float16* __restrict__ W1t,
    const float* __restrict__ W2, _Float16* __restrict__ W2t)
{
  int b = blockIdx.x, t = threadIdx.x;
  if (b >= NB){
    int b2 = b - NB;
    if (b2 < 128){
      W1t[t*128 + b2] = (_Float16)W1[b2*256 + t];
    } else {
      for (int i=t; i<4096; i+=256){ int k=i&255, j=i>>8; W2t[j*256+k] = (_Float16)W2[k*16+j]; }
    }
    return;
  }
  __shared__ unsigned int cnt[NW];
  for (int i=t; i<NW; i+=256) cnt[i] = 0u;
  __syncthreads();
  int e0 = b*chunk, e1 = e0+chunk; if (e1 > Etot) e1 = Etot;
  int e = e0 + t;
  for (; e + 768 < e1; e += 1024){
    int ea=e, eb=e+256, ec=e+512, ed=e+768;
    int d0 = (ea<E)?dstv[ea]:(ea-E);
    int d1 = (eb<E)?dstv[eb]:(eb-E);
    int d2 = (ec<E)?dstv[ec]:(ec-E);
    int d3 = (ed<E)?dstv[ed]:(ed-E);
    atomicAdd(&cnt[d0>>1], (d0&1)?65536u:1u);
    atomicAdd(&cnt[d1>>1], (d1&1)?65536u:1u);
    atomicAdd(&cnt[d2>>1], (d2&1)?65536u:1u);
    atomicAdd(&cnt[d3>>1], (d3&1)?65536u:1u);
  }
  for (; e < e1; e += 256){
    int d = (e<E)?dstv[e]:(e-E);
    atomicAdd(&cnt[d>>1], (d&1)?65536u:1u);
  }
  __syncthreads();
  unsigned int* dp = partial + (size_t)b*NW;
  for (int i=t; i<NW; i+=256) dp[i] = cnt[i];
}

// ---------------- scanA + scan1 fused ----------------
__global__ __launch_bounds__(256) void k_scanAB(unsigned long long* __restrict__ partial,
    int* __restrict__ rowptr, int* __restrict__ bsum, int N)
{
  __shared__ int lds[256];
  int t = threadIdx.x, blk = blockIdx.x;
  int base = blk*1024 + t*4;
  int r0=0, r1=0, r2=0, r3=0;
  if (base < N){
    unsigned long long* P = partial + (base >> 2);
    #pragma unroll 8
    for (int b=0; b<NB; ++b){
      unsigned long long v = P[(size_t)b*12500];
      unsigned long long pref =  (unsigned long long)(r0 & 0xffff)
        | ((unsigned long long)(r1 & 0xffff) << 16)
        | ((unsigned long long)(r2 & 0xffff) << 32)
        | ((unsigned long long)(r3 & 0xffff) << 48);
      P[(size_t)b*12500] = pref;
      r0 += (int)( v        & 0xffff);
      r1 += (int)((v >> 16) & 0xffff);
      r2 += (int)((v >> 32) & 0xffff);
      r3 += (int)((v >> 48) & 0xffff);
    }
  }
  int tot = r0+r1+r2+r3;
  lds[t] = tot; __syncthreads();
  for (int off=1; off<256; off<<=1){
    int add = (t>=off)?lds[t-off]:0;
    __syncthreads();
    lds[t] += add;
    __syncthreads();
  }
  int excl = lds[t] - tot;
  if (t==255) bsum[blk] = lds[t];
  int run = excl;
  if (base+0<N){ rowptr[base+0]=run; run+=r0; }
  if (base+1<N){ rowptr[base+1]=run; run+=r1; }
  if (base+2<N){ rowptr[base+2]=run; run+=r2; }
  if (base+3<N){ rowptr[base+3]=run; }
}

// ---------------- scatter (fuses scan2+scan3 redundantly per block) ----------------
__global__ __launch_bounds__(256) void k_scatter3(const int* __restrict__ srcv,
    const int* __restrict__ dstv, const int* __restrict__ rowptr,
    const unsigned short* __restrict__ pu, const int* __restrict__ bsum,
    int* __restrict__ csr_src, int E, int Etot, int chunk, int SB)
{
  __shared__ unsigned int cur[NW];
  __shared__ int bpre[64];
  int b = blockIdx.x, t = threadIdx.x;
  for (int i=t; i<NW; i+=256) cur[i] = 0u;
  if (t==0){ int run=0; for (int j=0;j<SB;++j){ bpre[j]=run; run+=bsum[j]; } }
  __syncthreads();
  const unsigned short* pb = pu + (size_t)b*NBINS;
  int e0 = b*chunk, e1 = e0+chunk; if (e1 > Etot) e1 = Etot;
  int e = e0 + t;
  for (; e + 768 < e1; e += 1024){
    int ea=e, eb=e+256, ec=e+512, ed=e+768;
    int d0,s0,d1,s1,d2,s2,d3,s3;
    if (ea<E){ d0=dstv[ea]; s0=srcv[ea]; } else { d0=ea-E; s0=d0; }
    if (eb<E){ d1=dstv[eb]; s1=srcv[eb]; } else { d1=eb-E; s1=d1; }
    if (ec<E){ d2=dstv[ec]; s2=srcv[ec]; } else { d2=ec-E; s2=d2; }
    if (ed<E){ d3=dstv[ed]; s3=srcv[ed]; } else { d3=ed-E; s3=d3; }
    int base0 = rowptr[d0] + bpre[d0>>10] + (int)pb[d0];
    int base1 = rowptr[d1] + bpre[d1>>10] + (int)pb[d1];
    int base2 = rowptr[d2] + bpre[d2>>10] + (int)pb[d2];
    int base3 = rowptr[d3] + bpre[d3>>10] + (int)pb[d3];
    unsigned int o0 = atomicAdd(&cur[d0>>1], (d0&1)?65536u:1u);
    csr_src[base0 + ((d0&1)?(int)(o0>>16):(int)(o0&0xffff))] = s0;
    unsigned int o1 = atomicAdd(&cur[d1>>1], (d1&1)?65536u:1u);
    csr_src[base1 + ((d1&1)?(int)(o1>>16):(int)(o1&0xffff))] = s1;
    unsigned int o2 = atomicAdd(&cur[d2>>1], (d2&1)?65536u:1u);
    csr_src[base2 + ((d2&1)?(int)(o2>>16):(int)(o2&0xffff))] = s2;
    unsigned int o3 = atomicAdd(&cur[d3>>1], (d3&1)?65536u:1u);
    csr_src[base3 + ((d3&1)?(int)(o3>>16):(int)(o3&0xffff))] = s3;
  }
  for (; e < e1; e += 256){
    int d,s;
    if (e<E){ d=dstv[e]; s=srcv[e]; } else { d=e-E; s=d; }
    int base = rowptr[d] + bpre[d>>10] + (int)pb[d];
    unsigned int o = atomicAdd(&cur[d>>1], (d&1)?65536u:1u);
    csr_src[base + ((d&1)?(int)(o>>16):(int)(o&0xffff))] = s;
  }
}

// ---------------- GEMM1 (MFMA) + rowptr finalize; h1 NODE-major fp16 ----------------
__global__ __launch_bounds__(256) void k_gemm1(const float* __restrict__ x,
    const _Float16* __restrict__ W1t, const float* __restrict__ as1,
    const float* __restrict__ ad1, _Float16* __restrict__ h1,
    float* __restrict__ a_src1, float* __restrict__ a_dst1,
    int* __restrict__ rowptr, const int* __restrict__ bsum, int SB, int Etot, int N)
{
  __shared__ char smem[33792];
  _Float16* As = (_Float16*)smem;           // [64 rows][136 halves] (272 B stride)
  int t = threadIdx.x;
  int n0 = blockIdx.x*64;

  if ((int)blockIdx.x < SB){
    int blk = blockIdx.x;
    int pref = 0;
    for (int j=0;j<blk;++j) pref += bsum[j];
    int i = blk*1024 + t*4;
    if (i+0 < N) rowptr[i+0] += pref;
    if (i+1 < N) rowptr[i+1] += pref;
    if (i+2 < N) rowptr[i+2] += pref;
    if (i+3 < N) rowptr[i+3] += pref;
    if (blk==0 && t==0) rowptr[N] = Etot;
  }

  #pragma unroll
  for (int it=0; it<8; ++it){
    int c = it*256 + t;
    int row = c >> 5;
    int c4  = c & 31;
    int gr = n0 + row; if (gr > N-1) gr = N-1;
    float4 v = *(const float4*)(x + (size_t)gr*128 + c4*4);
    _Float16* dp = As + row*136 + c4*4;
    dp[0]=(_Float16)v.x; dp[1]=(_Float16)v.y; dp[2]=(_Float16)v.z; dp[3]=(_Float16)v.w;
  }
  __syncthreads();

  int wv = t>>6, lane = t&63;
  int m = lane&15, q = lane>>4;
  int r0w = wv*16;

  f16x8 afr[4];
  #pragma unroll
  for (int ks=0; ks<4; ++ks)
    afr[ks] = *(const f16x8*)((const char*)As + (r0w+m)*272 + ks*64 + q*16);

  f32x4 acc[16];
  #pragma unroll
  for (int ct=0; ct<16; ++ct) acc[ct] = (f32x4){0.f,0.f,0.f,0.f};

  const char* bbase = (const char*)W1t;
  #pragma unroll
  for (int ct=0; ct<16; ++ct){
    const char* bp = bbase + (ct*16 + m)*256 + q*16;
    f16x8 b0 = *(const f16x8*)(bp);
    f16x8 b1 = *(const f16x8*)(bp+64);
    f16x8 b2 = *(const f16x8*)(bp+128);
    f16x8 b3 = *(const f16x8*)(bp+192);
    acc[ct] = __builtin_amdgcn_mfma_f32_16x16x32_f16(afr[0], b0, acc[ct],0,0,0);
    acc[ct] = __builtin_amdgcn_mfma_f32_16x16x32_f16(afr[1], b1, acc[ct],0,0,0);
    acc[ct] = __builtin_amdgcn_mfma_f32_16x16x32_f16(afr[2], b2, acc[ct],0,0,0);
    acc[ct] = __builtin_amdgcn_mfma_f32_16x16x32_f16(afr[3], b3, acc[ct],0,0,0);
  }
  __syncthreads();

  _Float16* Hs = (_Float16*)smem;           // [64][264] halves, 528B stride
  #pragma unroll
  for (int ct=0; ct<16; ++ct){
    #pragma unroll
    for (int r=0; r<4; ++r)
      Hs[(size_t)(r0w + q*4 + r)*264 + ct*16 + m] = (_Float16)acc[ct][r];
  }
  __syncthreads();

  for (int r=0; r<16; ++r){
    int grow = n0 + r0w + r;
    if (grow < N){
      uint2 v = *(const uint2*)((const char*)Hs + (size_t)(r0w+r)*528 + lane*8);
      *(uint2*)((char*)h1 + (size_t)grow*512 + lane*8) = v;
    }
  }

  #pragma unroll
  for (int p=t; p<512; p+=256){
    int row = p>>3, hd = p&7;
    int grow = n0 + row;
    if (grow < N){
      const _Float16* hr = Hs + (size_t)row*264 + hd*32;
      float sa=0.f, sd=0.f;
      #pragma unroll
      for (int c=0; c<32; ++c){
        float hv = (float)hr[c];
        sa += hv * as1[hd*32+c];
        sd += hv * ad1[hd*32+c];
      }
      a_src1[(size_t)grow*8+hd] = sa;
      a_dst1[(size_t)grow*8+hd] = sd;
    }
  }
}

// ---------------- Layer-1 aggregation (wave/dst, x8 unroll) + FUSED gemm2 epilogue ----------------
// Epilogue: stage fp32 h2 row to LDS (seg-staggered), lane(j=lane&15,seg=lane>>4)
// computes 64-long partial dot with W2t col j, butterfly-reduce segs -> hb,
// a_src2, a_dst2. NOTE: grid is exact (N%4==0) so no wave exits before barrier.
__global__ __launch_bounds__(256) void k_agg1(const __half* __restrict__ h1,
    const float* __restrict__ a_src1, const float* __restrict__ a_dst1,
    const int* __restrict__ rowptr, const int* __restrict__ csr_src,
    const float* __restrict__ bias1, const _Float16* __restrict__ W2t,
    const float* __restrict__ as2, const float* __restrict__ ad2,
    float* __restrict__ hb, float* __restrict__ a_src2, float* __restrict__ a_dst2, int N)
{
  __shared__ float Hrow[4][272];            // per-wave h2 row, +4 float stagger per seg
  int wvi  = threadIdx.x >> 6;
  int dst  = blockIdx.x*4 + wvi;
  int lane = threadIdx.x & 63;
  int head = lane >> 3;
  bool live = dst < N;
  int dcl = live ? dst : 0;
  float ad = a_dst1[(size_t)dcl*8 + head];
  int beg = rowptr[dcl], end = rowptr[dcl+1];
  float4 acc = make_float4(0.f,0.f,0.f,0.f);
  float wsum = 0.f;
  int i = beg;
  for (; i+8 <= end; i+=8){
    int s[8]; float e[8]; uint2 p[8];
    #pragma unroll
    for (int j=0;j<8;++j) s[j]=csr_src[i+j];
    #pragma unroll
    for (int j=0;j<8;++j){
      e[j]=a_src1[(size_t)s[j]*8+head];
      p[j]=*(const uint2*)((const char*)h1 + (size_t)s[j]*512 + lane*8);
    }
    #pragma unroll
    for (int j=0;j<8;++j){
      float w=__expf(lrelu(e[j]+ad));
      wsum += w;
      const __half2* qq=(const __half2*)&p[j];
      float2 f0=__half22float2(qq[0]), f1=__half22float2(qq[1]);
      acc.x += w*f0.x; acc.y += w*f0.y; acc.z += w*f1.x; acc.w += w*f1.y;
    }
  }
  for (; i+4 <= end; i+=4){
    int s[4]; float e[4]; uint2 p[4];
    #pragma unroll
    for (int j=0;j<4;++j) s[j]=csr_src[i+j];
    #pragma unroll
    for (int j=0;j<4;++j){
      e[j]=a_src1[(size_t)s[j]*8+head];
      p[j]=*(const uint2*)((const char*)h1 + (size_t)s[j]*512 + lane*8);
    }
    #pragma unroll
    for (int j=0;j<4;++j){
      float w=__expf(lrelu(e[j]+ad));
      wsum += w;
      const __half2* qq=(const __half2*)&p[j];
      float2 f0=__half22float2(qq[0]), f1=__half22float2(qq[1]);
      acc.x += w*f0.x; acc.y += w*f0.y; acc.z += w*f1.x; acc.w += w*f1.y;
    }
  }
  for (; i<end; ++i){
    int s = csr_src[i];
    float w = __expf(lrelu(a_src1[(size_t)s*8+head] + ad));
    wsum += w;
    uint2 p = *(const uint2*)((const char*)h1 + (size_t)s*512 + lane*8);
    const __half2* qq=(const __half2*)&p;
    float2 f0=__half22float2(qq[0]), f1=__half22float2(qq[1]);
    acc.x += w*f0.x; acc.y += w*f0.y; acc.z += w*f1.x; acc.w += w*f1.y;
  }
  float dinv = 1.f/(wsum + 1e-16f);
  const float4 bv = *(const float4*)(bias1 + lane*4);
  float4 o;
  o.x = acc.x*dinv + bv.x;
  o.y = acc.y*dinv + bv.y;
  o.z = acc.z*dinv + bv.z;
  o.w = acc.w*dinv + bv.w;
  o.x = o.x > 0.f ? o.x : __expf(o.x)-1.f;
  o.y = o.y > 0.f ? o.y : __expf(o.y)-1.f;
  o.z = o.z > 0.f ? o.z : __expf(o.z)-1.f;
  o.w = o.w > 0.f ? o.w : __expf(o.w)-1.f;

  // --- fused gemm2: hb[dst] = h2row @ W2, + a_src2/a_dst2 ---
  int seg = lane >> 4, j16 = lane & 15;
  // channel k=4*lane+r stored at index k + 4*(k/64) -> seg s starts at s*68
  *(float4*)&Hrow[wvi][4*lane + 4*seg] = o;
  __syncthreads();   // safe: N%4==0 -> all waves alive; only same-wave data read

  float part = 0.f;
  const _Float16* wcol = W2t + (size_t)j16*256 + seg*64;
  const float* hseg = &Hrow[wvi][seg*68];
  #pragma unroll
  for (int u=0; u<8; ++u){
    f16x8 wv8 = *(const f16x8*)(wcol + u*8);
    float4 hA = *(const float4*)(hseg + u*8);
    float4 hB = *(const float4*)(hseg + u*8 + 4);
    part += hA.x*(float)wv8[0] + hA.y*(float)wv8[1] + hA.z*(float)wv8[2] + hA.w*(float)wv8[3]
          + hB.x*(float)wv8[4] + hB.y*(float)wv8[5] + hB.z*(float)wv8[6] + hB.w*(float)wv8[7];
  }
  part += __shfl_xor(part, 16);
  part += __shfl_xor(part, 32);              // all lanes now hold hb[dst][j16]
  float pa = part * as2[j16], pd = part * ad2[j16];
  #pragma unroll
  for (int msk=8; msk>=1; msk>>=1){ pa += __shfl_xor(pa,msk); pd += __shfl_xor(pd,msk); }
  if (live && seg==0){
    hb[(size_t)dst*16 + j16] = part;
    if (j16==0){ a_src2[dst] = pa; a_dst2[dst] = pd; }
  }
}

// ---------------- Layer-2 aggregation: wave per dst, 4 edge-groups x 16 ch ----------------
__global__ __launch_bounds__(256) void k_agg2(const float* __restrict__ hb,
    const float* __restrict__ a_src2, const float* __restrict__ a_dst2,
    const int* __restrict__ rowptr, const int* __restrict__ csr_src,
    const float* __restrict__ bias2, float* __restrict__ out, int N)
{
  int wave = (blockIdx.x*blockDim.x + threadIdx.x) >> 6;
  if (wave >= N) return;
  int lane = threadIdx.x & 63;
  int eg   = lane >> 4;
  int ch   = lane & 15;
  float ad = a_dst2[wave];
  int beg = rowptr[wave], end = rowptr[wave+1];
  float acc = 0.f, wsum = 0.f;
  int i = beg + eg;
  for (; i+4 < end; i+=8){
    int s0 = csr_src[i], s1 = csr_src[i+4];
    float e0 = a_src2[s0], e1 = a_src2[s1];
    float h0 = hb[(size_t)s0*16 + ch], h1v = hb[(size_t)s1*16 + ch];
    float w0 = __expf(lrelu(e0 + ad)), w1 = __expf(lrelu(e1 + ad));
    wsum += w0 + w1;
    acc += w0*h0 + w1*h1v;
  }
  for (; i<end; i+=4){
    int s = csr_src[i];
    float w = __expf(lrelu(a_src2[s] + ad));
    wsum += w;
    acc += w * hb[(size_t)s*16 + ch];
  }
  acc  += __shfl_xor(acc, 16);  acc  += __shfl_xor(acc, 32);
  wsum += __shfl_xor(wsum, 16); wsum += __shfl_xor(wsum, 32);
  if (eg == 0)
    out[(size_t)wave*16 + ch] = acc/(wsum + 1e-16f) + bias2[ch];
}

extern "C" void kernel_launch(void* const* d_in, const int* in_sizes, int n_in,
                              void* d_out, int out_size, void* d_ws, size_t ws_size,
                              hipStream_t stream)
{
  const float* x   = (const float*)d_in[0];
  const int*   ei  = (const int*)  d_in[1];
  const float* W1  = (const float*)d_in[2];
  const float* as1 = (const float*)d_in[3];
  const float* ad1 = (const float*)d_in[4];
  const float* b1  = (const float*)d_in[5];
  const float* W2  = (const float*)d_in[6];
  const float* as2 = (const float*)d_in[7];
  const float* ad2 = (const float*)d_in[8];
  const float* b2  = (const float*)d_in[9];
  float* out = (float*)d_out;

  const int N    = in_sizes[0] / 128;       // 50000
  const int E    = in_sizes[1] / 2;         // 800000
  const int Etot = E + N;
  const int* srcv = ei;
  const int* dstv = ei + E;
  const int chunk = (Etot + NB - 1) / NB;   // 13282 < 65536 (u16-field safe)
  const int SB    = (N + 1023) / 1024;      // 49 scan blocks

  char* p = (char*)d_ws;
  auto alloc = [&](size_t bytes)->void* {
    void* r = (void*)p;
    p += (bytes + 255) & ~((size_t)255);
    return r;
  };
  _Float16* h1   = (_Float16*)alloc((size_t)N*256*sizeof(_Float16));   // node-major [N][256]
  _Float16* W1t  = (_Float16*)alloc((size_t)256*128*sizeof(_Float16));
  _Float16* W2t  = (_Float16*)alloc((size_t)16*256*sizeof(_Float16));
  float* a_src1  = (float*)alloc((size_t)N*8*sizeof(float));
  float* a_dst1  = (float*)alloc((size_t)N*8*sizeof(float));
  float* hb      = (float*)alloc((size_t)N*16*sizeof(float));
  float* a_src2  = (float*)alloc((size_t)N*sizeof(float));
  float* a_dst2  = (float*)alloc((size_t)N*sizeof(float));
  int*   rowptr  = (int*)alloc((size_t)(N+1)*sizeof(int));
  int*   bsum    = (int*)alloc(256*sizeof(int));
  unsigned int* partial = (unsigned int*)alloc((size_t)NB*NW*sizeof(unsigned int));
  int*   csr_src = (int*)alloc((size_t)Etot*sizeof(int));

  // 1. histogram (packed u16) + weight prep
  k_histW<<<dim3(NB+129), dim3(256), 0, stream>>>(dstv, partial, E, Etot, chunk,
                                                  W1, W1t, W2, W2t);
  // 2. per-bin partial prefix + block-local rowptr + bsum
  k_scanAB<<<dim3(SB), dim3(256), 0, stream>>>((unsigned long long*)partial, rowptr, bsum, N);
  // 3. deterministic scatter
  k_scatter3<<<dim3(NB), dim3(256), 0, stream>>>(srcv, dstv, rowptr,
      (const unsigned short*)partial, bsum, csr_src, E, Etot, chunk, SB);
  // 4. GEMM1 (node-major h1; also finalizes rowptr)
  k_gemm1<<<dim3((N + 63)/64), dim3(256), 0, stream>>>(x, W1t, as1, ad1, h1,
      a_src1, a_dst1, rowptr, bsum, SB, Etot, N);
  // 5. agg1 + fused gemm2 epilogue
  k_agg1<<<dim3((N + 3)/4), dim3(256), 0, stream>>>((const __half*)h1, a_src1, a_dst1,
      rowptr, csr_src, b1, W2t, as2, ad2, hb, a_src2, a_dst2, N);
  // 6. agg2
  k_agg2<<<dim3((N + 3)/4), dim3(256), 0, stream>>>(hb, a_src2, a_dst2, rowptr, csr_src, b2, out, N);
}

// Round 9
// 312.888 us; speedup vs baseline: 1.2023x; 1.0302x over previous
//
#include <hip/hip_runtime.h>
#include <hip/hip_fp16.h>
#include <math.h>

// 2-layer GAT. N=50000, E=800000 (+N self loops), F=128, H=8, C=32, NCLS=16.
// R9: R8's fused agg1+gemm2 kept, but the epilogue __syncthreads() REMOVED.
// R8 post-mortem: the barrier coupled the block's 4 waves -> every block ran at
// max(degree of 4 dsts) ~= 1.5x mean (70->109us). The barrier is unnecessary:
// each wave reads only its own Hrow[wvi] slice, and wave64 is lockstep on CDNA
// (compiler inserts lgkmcnt between ds_write and ds_read). Waves now retire
// independently again, keeping the fusion's wins (no gemm2 kernel, -21MB WRITE).

#define NB    64
#define NBINS 50000
#define NW    25000

typedef _Float16 f16x8 __attribute__((ext_vector_type(8)));
typedef float    f32x4 __attribute__((ext_vector_type(4)));

__device__ __forceinline__ float lrelu(float v){ return v > 0.f ? v : 0.2f*v; }

// ---------------- hist (packed u16) + weight prep ----------------
__global__ __launch_bounds__(256) void k_histW(const int* __restrict__ dstv,
    unsigned int* __restrict__ partial, int E, int Etot, int chunk,
    const float* __restrict__ W1, _Float16* __restrict__ W1t,
    const float* __restrict__ W2, _Float16* __restrict__ W2t)
{
  int b = blockIdx.x, t = threadIdx.x;
  if (b >= NB){
    int b2 = b - NB;
    if (b2 < 128){
      W1t[t*128 + b2] = (_Float16)W1[b2*256 + t];
    } else {
      for (int i=t; i<4096; i+=256){ int k=i&255, j=i>>8; W2t[j*256+k] = (_Float16)W2[k*16+j]; }
    }
    return;
  }
  __shared__ unsigned int cnt[NW];
  for (int i=t; i<NW; i+=256) cnt[i] = 0u;
  __syncthreads();
  int e0 = b*chunk, e1 = e0+chunk; if (e1 > Etot) e1 = Etot;
  int e = e0 + t;
  for (; e + 768 < e1; e += 1024){
    int ea=e, eb=e+256, ec=e+512, ed=e+768;
    int d0 = (ea<E)?dstv[ea]:(ea-E);
    int d1 = (eb<E)?dstv[eb]:(eb-E);
    int d2 = (ec<E)?dstv[ec]:(ec-E);
    int d3 = (ed<E)?dstv[ed]:(ed-E);
    atomicAdd(&cnt[d0>>1], (d0&1)?65536u:1u);
    atomicAdd(&cnt[d1>>1], (d1&1)?65536u:1u);
    atomicAdd(&cnt[d2>>1], (d2&1)?65536u:1u);
    atomicAdd(&cnt[d3>>1], (d3&1)?65536u:1u);
  }
  for (; e < e1; e += 256){
    int d = (e<E)?dstv[e]:(e-E);
    atomicAdd(&cnt[d>>1], (d&1)?65536u:1u);
  }
  __syncthreads();
  unsigned int* dp = partial + (size_t)b*NW;
  for (int i=t; i<NW; i+=256) dp[i] = cnt[i];
}

// ---------------- scanA + scan1 fused ----------------
__global__ __launch_bounds__(256) void k_scanAB(unsigned long long* __restrict__ partial,
    int* __restrict__ rowptr, int* __restrict__ bsum, int N)
{
  __shared__ int lds[256];
  int t = threadIdx.x, blk = blockIdx.x;
  int base = blk*1024 + t*4;
  int r0=0, r1=0, r2=0, r3=0;
  if (base < N){
    unsigned long long* P = partial + (base >> 2);
    #pragma unroll 8
    for (int b=0; b<NB; ++b){
      unsigned long long v = P[(size_t)b*12500];
      unsigned long long pref =  (unsigned long long)(r0 & 0xffff)
        | ((unsigned long long)(r1 & 0xffff) << 16)
        | ((unsigned long long)(r2 & 0xffff) << 32)
        | ((unsigned long long)(r3 & 0xffff) << 48);
      P[(size_t)b*12500] = pref;
      r0 += (int)( v        & 0xffff);
      r1 += (int)((v >> 16) & 0xffff);
      r2 += (int)((v >> 32) & 0xffff);
      r3 += (int)((v >> 48) & 0xffff);
    }
  }
  int tot = r0+r1+r2+r3;
  lds[t] = tot; __syncthreads();
  for (int off=1; off<256; off<<=1){
    int add = (t>=off)?lds[t-off]:0;
    __syncthreads();
    lds[t] += add;
    __syncthreads();
  }
  int excl = lds[t] - tot;
  if (t==255) bsum[blk] = lds[t];
  int run = excl;
  if (base+0<N){ rowptr[base+0]=run; run+=r0; }
  if (base+1<N){ rowptr[base+1]=run; run+=r1; }
  if (base+2<N){ rowptr[base+2]=run; run+=r2; }
  if (base+3<N){ rowptr[base+3]=run; }
}

// ---------------- scatter (fuses scan2+scan3 redundantly per block) ----------------
__global__ __launch_bounds__(256) void k_scatter3(const int* __restrict__ srcv,
    const int* __restrict__ dstv, const int* __restrict__ rowptr,
    const unsigned short* __restrict__ pu, const int* __restrict__ bsum,
    int* __restrict__ csr_src, int E, int Etot, int chunk, int SB)
{
  __shared__ unsigned int cur[NW];
  __shared__ int bpre[64];
  int b = blockIdx.x, t = threadIdx.x;
  for (int i=t; i<NW; i+=256) cur[i] = 0u;
  if (t==0){ int run=0; for (int j=0;j<SB;++j){ bpre[j]=run; run+=bsum[j]; } }
  __syncthreads();
  const unsigned short* pb = pu + (size_t)b*NBINS;
  int e0 = b*chunk, e1 = e0+chunk; if (e1 > Etot) e1 = Etot;
  int e = e0 + t;
  for (; e + 768 < e1; e += 1024){
    int ea=e, eb=e+256, ec=e+512, ed=e+768;
    int d0,s0,d1,s1,d2,s2,d3,s3;
    if (ea<E){ d0=dstv[ea]; s0=srcv[ea]; } else { d0=ea-E; s0=d0; }
    if (eb<E){ d1=dstv[eb]; s1=srcv[eb]; } else { d1=eb-E; s1=d1; }
    if (ec<E){ d2=dstv[ec]; s2=srcv[ec]; } else { d2=ec-E; s2=d2; }
    if (ed<E){ d3=dstv[ed]; s3=srcv[ed]; } else { d3=ed-E; s3=d3; }
    int base0 = rowptr[d0] + bpre[d0>>10] + (int)pb[d0];
    int base1 = rowptr[d1] + bpre[d1>>10] + (int)pb[d1];
    int base2 = rowptr[d2] + bpre[d2>>10] + (int)pb[d2];
    int base3 = rowptr[d3] + bpre[d3>>10] + (int)pb[d3];
    unsigned int o0 = atomicAdd(&cur[d0>>1], (d0&1)?65536u:1u);
    csr_src[base0 + ((d0&1)?(int)(o0>>16):(int)(o0&0xffff))] = s0;
    unsigned int o1 = atomicAdd(&cur[d1>>1], (d1&1)?65536u:1u);
    csr_src[base1 + ((d1&1)?(int)(o1>>16):(int)(o1&0xffff))] = s1;
    unsigned int o2 = atomicAdd(&cur[d2>>1], (d2&1)?65536u:1u);
    csr_src[base2 + ((d2&1)?(int)(o2>>16):(int)(o2&0xffff))] = s2;
    unsigned int o3 = atomicAdd(&cur[d3>>1], (d3&1)?65536u:1u);
    csr_src[base3 + ((d3&1)?(int)(o3>>16):(int)(o3&0xffff))] = s3;
  }
  for (; e < e1; e += 256){
    int d,s;
    if (e<E){ d=dstv[e]; s=srcv[e]; } else { d=e-E; s=d; }
    int base = rowptr[d] + bpre[d>>10] + (int)pb[d];
    unsigned int o = atomicAdd(&cur[d>>1], (d&1)?65536u:1u);
    csr_src[base + ((d&1)?(int)(o>>16):(int)(o&0xffff))] = s;
  }
}

// ---------------- GEMM1 (MFMA) + rowptr finalize; h1 NODE-major fp16 ----------------
__global__ __launch_bounds__(256) void k_gemm1(const float* __restrict__ x,
    const _Float16* __restrict__ W1t, const float* __restrict__ as1,
    const float* __restrict__ ad1, _Float16* __restrict__ h1,
    float* __restrict__ a_src1, float* __restrict__ a_dst1,
    int* __restrict__ rowptr, const int* __restrict__ bsum, int SB, int Etot, int N)
{
  __shared__ char smem[33792];
  _Float16* As = (_Float16*)smem;           // [64 rows][136 halves] (272 B stride)
  int t = threadIdx.x;
  int n0 = blockIdx.x*64;

  if ((int)blockIdx.x < SB){
    int blk = blockIdx.x;
    int pref = 0;
    for (int j=0;j<blk;++j) pref += bsum[j];
    int i = blk*1024 + t*4;
    if (i+0 < N) rowptr[i+0] += pref;
    if (i+1 < N) rowptr[i+1] += pref;
    if (i+2 < N) rowptr[i+2] += pref;
    if (i+3 < N) rowptr[i+3] += pref;
    if (blk==0 && t==0) rowptr[N] = Etot;
  }

  #pragma unroll
  for (int it=0; it<8; ++it){
    int c = it*256 + t;
    int row = c >> 5;
    int c4  = c & 31;
    int gr = n0 + row; if (gr > N-1) gr = N-1;
    float4 v = *(const float4*)(x + (size_t)gr*128 + c4*4);
    _Float16* dp = As + row*136 + c4*4;
    dp[0]=(_Float16)v.x; dp[1]=(_Float16)v.y; dp[2]=(_Float16)v.z; dp[3]=(_Float16)v.w;
  }
  __syncthreads();

  int wv = t>>6, lane = t&63;
  int m = lane&15, q = lane>>4;
  int r0w = wv*16;

  f16x8 afr[4];
  #pragma unroll
  for (int ks=0; ks<4; ++ks)
    afr[ks] = *(const f16x8*)((const char*)As + (r0w+m)*272 + ks*64 + q*16);

  f32x4 acc[16];
  #pragma unroll
  for (int ct=0; ct<16; ++ct) acc[ct] = (f32x4){0.f,0.f,0.f,0.f};

  const char* bbase = (const char*)W1t;
  #pragma unroll
  for (int ct=0; ct<16; ++ct){
    const char* bp = bbase + (ct*16 + m)*256 + q*16;
    f16x8 b0 = *(const f16x8*)(bp);
    f16x8 b1 = *(const f16x8*)(bp+64);
    f16x8 b2 = *(const f16x8*)(bp+128);
    f16x8 b3 = *(const f16x8*)(bp+192);
    acc[ct] = __builtin_amdgcn_mfma_f32_16x16x32_f16(afr[0], b0, acc[ct],0,0,0);
    acc[ct] = __builtin_amdgcn_mfma_f32_16x16x32_f16(afr[1], b1, acc[ct],0,0,0);
    acc[ct] = __builtin_amdgcn_mfma_f32_16x16x32_f16(afr[2], b2, acc[ct],0,0,0);
    acc[ct] = __builtin_amdgcn_mfma_f32_16x16x32_f16(afr[3], b3, acc[ct],0,0,0);
  }
  __syncthreads();

  _Float16* Hs = (_Float16*)smem;           // [64][264] halves, 528B stride
  #pragma unroll
  for (int ct=0; ct<16; ++ct){
    #pragma unroll
    for (int r=0; r<4; ++r)
      Hs[(size_t)(r0w + q*4 + r)*264 + ct*16 + m] = (_Float16)acc[ct][r];
  }
  __syncthreads();

  for (int r=0; r<16; ++r){
    int grow = n0 + r0w + r;
    if (grow < N){
      uint2 v = *(const uint2*)((const char*)Hs + (size_t)(r0w+r)*528 + lane*8);
      *(uint2*)((char*)h1 + (size_t)grow*512 + lane*8) = v;
    }
  }

  #pragma unroll
  for (int p=t; p<512; p+=256){
    int row = p>>3, hd = p&7;
    int grow = n0 + row;
    if (grow < N){
      const _Float16* hr = Hs + (size_t)row*264 + hd*32;
      float sa=0.f, sd=0.f;
      #pragma unroll
      for (int c=0; c<32; ++c){
        float hv = (float)hr[c];
        sa += hv * as1[hd*32+c];
        sd += hv * ad1[hd*32+c];
      }
      a_src1[(size_t)grow*8+hd] = sa;
      a_dst1[(size_t)grow*8+hd] = sd;
    }
  }
}

// ---------------- Layer-1 aggregation (wave/dst, x8 unroll) + FUSED gemm2 epilogue ----------------
// Wave-synchronous epilogue: each wave writes/reads only Hrow[wvi]; no block
// barrier (R8's __syncthreads coupled 4 waves -> max-degree gating, +55%).
__global__ __launch_bounds__(256) void k_agg1(const __half* __restrict__ h1,
    const float* __restrict__ a_src1, const float* __restrict__ a_dst1,
    const int* __restrict__ rowptr, const int* __restrict__ csr_src,
    const float* __restrict__ bias1, const _Float16* __restrict__ W2t,
    const float* __restrict__ as2, const float* __restrict__ ad2,
    float* __restrict__ hb, float* __restrict__ a_src2, float* __restrict__ a_dst2, int N)
{
  __shared__ float Hrow[4][272];            // per-wave h2 row, +4 float stagger per seg
  int wvi  = threadIdx.x >> 6;
  int dst  = blockIdx.x*4 + wvi;
  if (dst >= N) return;
  int lane = threadIdx.x & 63;
  int head = lane >> 3;
  float ad = a_dst1[(size_t)dst*8 + head];
  int beg = rowptr[dst], end = rowptr[dst+1];
  float4 acc = make_float4(0.f,0.f,0.f,0.f);
  float wsum = 0.f;
  int i = beg;
  for (; i+8 <= end; i+=8){
    int s[8]; float e[8]; uint2 p[8];
    #pragma unroll
    for (int j=0;j<8;++j) s[j]=csr_src[i+j];
    #pragma unroll
    for (int j=0;j<8;++j){
      e[j]=a_src1[(size_t)s[j]*8+head];
      p[j]=*(const uint2*)((const char*)h1 + (size_t)s[j]*512 + lane*8);
    }
    #pragma unroll
    for (int j=0;j<8;++j){
      float w=__expf(lrelu(e[j]+ad));
      wsum += w;
      const __half2* qq=(const __half2*)&p[j];
      float2 f0=__half22float2(qq[0]), f1=__half22float2(qq[1]);
      acc.x += w*f0.x; acc.y += w*f0.y; acc.z += w*f1.x; acc.w += w*f1.y;
    }
  }
  for (; i+4 <= end; i+=4){
    int s[4]; float e[4]; uint2 p[4];
    #pragma unroll
    for (int j=0;j<4;++j) s[j]=csr_src[i+j];
    #pragma unroll
    for (int j=0;j<4;++j){
      e[j]=a_src1[(size_t)s[j]*8+head];
      p[j]=*(const uint2*)((const char*)h1 + (size_t)s[j]*512 + lane*8);
    }
    #pragma unroll
    for (int j=0;j<4;++j){
      float w=__expf(lrelu(e[j]+ad));
      wsum += w;
      const __half2* qq=(const __half2*)&p[j];
      float2 f0=__half22float2(qq[0]), f1=__half22float2(qq[1]);
      acc.x += w*f0.x; acc.y += w*f0.y; acc.z += w*f1.x; acc.w += w*f1.y;
    }
  }
  for (; i<end; ++i){
    int s = csr_src[i];
    float w = __expf(lrelu(a_src1[(size_t)s*8+head] + ad));
    wsum += w;
    uint2 p = *(const uint2*)((const char*)h1 + (size_t)s*512 + lane*8);
    const __half2* qq=(const __half2*)&p;
    float2 f0=__half22float2(qq[0]), f1=__half22float2(qq[1]);
    acc.x += w*f0.x; acc.y += w*f0.y; acc.z += w*f1.x; acc.w += w*f1.y;
  }
  float dinv = 1.f/(wsum + 1e-16f);
  const float4 bv = *(const float4*)(bias1 + lane*4);
  float4 o;
  o.x = acc.x*dinv + bv.x;
  o.y = acc.y*dinv + bv.y;
  o.z = acc.z*dinv + bv.z;
  o.w = acc.w*dinv + bv.w;
  o.x = o.x > 0.f ? o.x : __expf(o.x)-1.f;
  o.y = o.y > 0.f ? o.y : __expf(o.y)-1.f;
  o.z = o.z > 0.f ? o.z : __expf(o.z)-1.f;
  o.w = o.w > 0.f ? o.w : __expf(o.w)-1.f;

  // --- fused gemm2 (wave-synchronous, no barrier): hb[dst] = h2row @ W2 ---
  int seg = lane >> 4, j16 = lane & 15;
  // channel k=4*lane+r stored at index k + 4*(k/64) -> seg s starts at s*68
  *(float4*)&Hrow[wvi][4*lane + 4*seg] = o;
  // intra-wave LDS write->read: compiler inserts lgkmcnt wait; wave64 lockstep.

  float part = 0.f;
  const _Float16* wcol = W2t + (size_t)j16*256 + seg*64;
  const float* hseg = &Hrow[wvi][seg*68];
  #pragma unroll
  for (int u=0; u<8; ++u){
    f16x8 wv8 = *(const f16x8*)(wcol + u*8);
    float4 hA = *(const float4*)(hseg + u*8);
    float4 hB = *(const float4*)(hseg + u*8 + 4);
    part += hA.x*(float)wv8[0] + hA.y*(float)wv8[1] + hA.z*(float)wv8[2] + hA.w*(float)wv8[3]
          + hB.x*(float)wv8[4] + hB.y*(float)wv8[5] + hB.z*(float)wv8[6] + hB.w*(float)wv8[7];
  }
  part += __shfl_xor(part, 16);
  part += __shfl_xor(part, 32);              // all lanes now hold hb[dst][j16]
  float pa = part * as2[j16], pd = part * ad2[j16];
  #pragma unroll
  for (int msk=8; msk>=1; msk>>=1){ pa += __shfl_xor(pa,msk); pd += __shfl_xor(pd,msk); }
  if (seg==0){
    hb[(size_t)dst*16 + j16] = part;
    if (j16==0){ a_src2[dst] = pa; a_dst2[dst] = pd; }
  }
}

// ---------------- Layer-2 aggregation: wave per dst, 4 edge-groups x 16 ch ----------------
__global__ __launch_bounds__(256) void k_agg2(const float* __restrict__ hb,
    const float* __restrict__ a_src2, const float* __restrict__ a_dst2,
    const int* __restrict__ rowptr, const int* __restrict__ csr_src,
    const float* __restrict__ bias2, float* __restrict__ out, int N)
{
  int wave = (blockIdx.x*blockDim.x + threadIdx.x) >> 6;
  if (wave >= N) return;
  int lane = threadIdx.x & 63;
  int eg   = lane >> 4;
  int ch   = lane & 15;
  float ad = a_dst2[wave];
  int beg = rowptr[wave], end = rowptr[wave+1];
  float acc = 0.f, wsum = 0.f;
  int i = beg + eg;
  for (; i+4 < end; i+=8){
    int s0 = csr_src[i], s1 = csr_src[i+4];
    float e0 = a_src2[s0], e1 = a_src2[s1];
    float h0 = hb[(size_t)s0*16 + ch], h1v = hb[(size_t)s1*16 + ch];
    float w0 = __expf(lrelu(e0 + ad)), w1 = __expf(lrelu(e1 + ad));
    wsum += w0 + w1;
    acc += w0*h0 + w1*h1v;
  }
  for (; i<end; i+=4){
    int s = csr_src[i];
    float w = __expf(lrelu(a_src2[s] + ad));
    wsum += w;
    acc += w * hb[(size_t)s*16 + ch];
  }
  acc  += __shfl_xor(acc, 16);  acc  += __shfl_xor(acc, 32);
  wsum += __shfl_xor(wsum, 16); wsum += __shfl_xor(wsum, 32);
  if (eg == 0)
    out[(size_t)wave*16 + ch] = acc/(wsum + 1e-16f) + bias2[ch];
}

extern "C" void kernel_launch(void* const* d_in, const int* in_sizes, int n_in,
                              void* d_out, int out_size, void* d_ws, size_t ws_size,
                              hipStream_t stream)
{
  const float* x   = (const float*)d_in[0];
  const int*   ei  = (const int*)  d_in[1];
  const float* W1  = (const float*)d_in[2];
  const float* as1 = (const float*)d_in[3];
  const float* ad1 = (const float*)d_in[4];
  const float* b1  = (const float*)d_in[5];
  const float* W2  = (const float*)d_in[6];
  const float* as2 = (const float*)d_in[7];
  const float* ad2 = (const float*)d_in[8];
  const float* b2  = (const float*)d_in[9];
  float* out = (float*)d_out;

  const int N    = in_sizes[0] / 128;       // 50000
  const int E    = in_sizes[1] / 2;         // 800000
  const int Etot = E + N;
  const int* srcv = ei;
  const int* dstv = ei + E;
  const int chunk = (Etot + NB - 1) / NB;   // 13282 < 65536 (u16-field safe)
  const int SB    = (N + 1023) / 1024;      // 49 scan blocks

  char* p = (char*)d_ws;
  auto alloc = [&](size_t bytes)->void* {
    void* r = (void*)p;
    p += (bytes + 255) & ~((size_t)255);
    return r;
  };
  _Float16* h1   = (_Float16*)alloc((size_t)N*256*sizeof(_Float16));   // node-major [N][256]
  _Float16* W1t  = (_Float16*)alloc((size_t)256*128*sizeof(_Float16));
  _Float16* W2t  = (_Float16*)alloc((size_t)16*256*sizeof(_Float16));
  float* a_src1  = (float*)alloc((size_t)N*8*sizeof(float));
  float* a_dst1  = (float*)alloc((size_t)N*8*sizeof(float));
  float* hb      = (float*)alloc((size_t)N*16*sizeof(float));
  float* a_src2  = (float*)alloc((size_t)N*sizeof(float));
  float* a_dst2  = (float*)alloc((size_t)N*sizeof(float));
  int*   rowptr  = (int*)alloc((size_t)(N+1)*sizeof(int));
  int*   bsum    = (int*)alloc(256*sizeof(int));
  unsigned int* partial = (unsigned int*)alloc((size_t)NB*NW*sizeof(unsigned int));
  int*   csr_src = (int*)alloc((size_t)Etot*sizeof(int));

  // 1. histogram (packed u16) + weight prep
  k_histW<<<dim3(NB+129), dim3(256), 0, stream>>>(dstv, partial, E, Etot, chunk,
                                                  W1, W1t, W2, W2t);
  // 2. per-bin partial prefix + block-local rowptr + bsum
  k_scanAB<<<dim3(SB), dim3(256), 0, stream>>>((unsigned long long*)partial, rowptr, bsum, N);
  // 3. deterministic scatter
  k_scatter3<<<dim3(NB), dim3(256), 0, stream>>>(srcv, dstv, rowptr,
      (const unsigned short*)partial, bsum, csr_src, E, Etot, chunk, SB);
  // 4. GEMM1 (node-major h1; also finalizes rowptr)
  k_gemm1<<<dim3((N + 63)/64), dim3(256), 0, stream>>>(x, W1t, as1, ad1, h1,
      a_src1, a_dst1, rowptr, bsum, SB, Etot, N);
  // 5. agg1 + fused gemm2 epilogue (barrier-free)
  k_agg1<<<dim3((N + 3)/4), dim3(256), 0, stream>>>((const __half*)h1, a_src1, a_dst1,
      rowptr, csr_src, b1, W2t, as2, ad2, hb, a_src2, a_dst2, N);
  // 6. agg2
  k_agg2<<<dim3((N + 3)/4), dim3(256), 0, stream>>>(hb, a_src2, a_dst2, rowptr, csr_src, b2, out, N);
}

// Round 11
// 294.123 us; speedup vs baseline: 1.2790x; 1.0638x over previous
//
#include <hip/hip_runtime.h>
#include <hip/hip_fp16.h>
#include <math.h>

// 2-layer GAT. N=50000, E=800000 (+N self loops), F=128, H=8, C=32, NCLS=16.
// R11: coop launch (R10) abandoned -- runtime rejected the 1024-block grid
// (out never written). Revert to R6 bodies, restructured to 6 launches:
//   K1 histW      : packed-u16 hist (64 blk) + weight prep (129 blk)   [R6]
//   K2 g1scan     : blocks 0..SB-1 = scanAB; blocks SB.. = gemm1 tiles
//                   (mutually independent, scan hides under gemm1)
//   K3 scatter3   : scatter + writes rowfin[] = finalized rowptr (no race:
//                   scatter reads local rowptr, finalize writes rowfin only)
//   K4 agg1 / K5 gemm2 / K6 agg2 (consume rowfin)                      [R6]

#define NB    64
#define NBINS 50000
#define NW    25000

typedef _Float16 f16x8 __attribute__((ext_vector_type(8)));
typedef _Float16 f16x4 __attribute__((ext_vector_type(4)));
typedef float    f32x4 __attribute__((ext_vector_type(4)));

__device__ __forceinline__ float lrelu(float v){ return v > 0.f ? v : 0.2f*v; }

// ---------------- K1: hist (packed u16) + weight prep ----------------
__global__ __launch_bounds__(256) void k_histW(const int* __restrict__ dstv,
    unsigned int* __restrict__ partial, int E, int Etot, int chunk,
    const float* __restrict__ W1, _Float16* __restrict__ W1t,
    const float* __restrict__ W2, _Float16* __restrict__ W2t)
{
  int b = blockIdx.x, t = threadIdx.x;
  if (b >= NB){
    int b2 = b - NB;
    if (b2 < 128){
      W1t[t*128 + b2] = (_Float16)W1[b2*256 + t];
    } else {
      for (int i=t; i<4096; i+=256){ int k=i&255, j=i>>8; W2t[j*256+k] = (_Float16)W2[k*16+j]; }
    }
    return;
  }
  __shared__ unsigned int cnt[NW];
  for (int i=t; i<NW; i+=256) cnt[i] = 0u;
  __syncthreads();
  int e0 = b*chunk, e1 = e0+chunk; if (e1 > Etot) e1 = Etot;
  int e = e0 + t;
  for (; e + 768 < e1; e += 1024){
    int ea=e, eb=e+256, ec=e+512, ed=e+768;
    int d0 = (ea<E)?dstv[ea]:(ea-E);
    int d1 = (eb<E)?dstv[eb]:(eb-E);
    int d2 = (ec<E)?dstv[ec]:(ec-E);
    int d3 = (ed<E)?dstv[ed]:(ed-E);
    atomicAdd(&cnt[d0>>1], (d0&1)?65536u:1u);
    atomicAdd(&cnt[d1>>1], (d1&1)?65536u:1u);
    atomicAdd(&cnt[d2>>1], (d2&1)?65536u:1u);
    atomicAdd(&cnt[d3>>1], (d3&1)?65536u:1u);
  }
  for (; e < e1; e += 256){
    int d = (e<E)?dstv[e]:(e-E);
    atomicAdd(&cnt[d>>1], (d&1)?65536u:1u);
  }
  __syncthreads();
  unsigned int* dp = partial + (size_t)b*NW;
  for (int i=t; i<NW; i+=256) dp[i] = cnt[i];
}

// ---------------- K2: scanAB (blocks 0..SB-1) + GEMM1 tiles (blocks SB..) ----------------
__global__ __launch_bounds__(256) void k_g1scan(const float* __restrict__ x,
    const _Float16* __restrict__ W1t, const float* __restrict__ as1,
    const float* __restrict__ ad1, _Float16* __restrict__ h1,
    float* __restrict__ a_src1, float* __restrict__ a_dst1,
    unsigned long long* __restrict__ partial, int* __restrict__ rowptr,
    int* __restrict__ bsum, int N, int SB)
{
  __shared__ char smem[33792];
  int t = threadIdx.x;
  int b = blockIdx.x;

  if (b < SB){
    // ---- scanAB: per-bin partial prefix (u64 over 4 bins) + block scan ----
    int* lds = (int*)smem;
    int base = b*1024 + t*4;
    int r0=0, r1=0, r2=0, r3=0;
    if (base < N){
      unsigned long long* P = partial + (base >> 2);
      #pragma unroll 8
      for (int bb=0; bb<NB; ++bb){
        unsigned long long v = P[(size_t)bb*12500];
        unsigned long long pref =  (unsigned long long)(r0 & 0xffff)
          | ((unsigned long long)(r1 & 0xffff) << 16)
          | ((unsigned long long)(r2 & 0xffff) << 32)
          | ((unsigned long long)(r3 & 0xffff) << 48);
        P[(size_t)bb*12500] = pref;
        r0 += (int)( v        & 0xffff);
        r1 += (int)((v >> 16) & 0xffff);
        r2 += (int)((v >> 32) & 0xffff);
        r3 += (int)((v >> 48) & 0xffff);
      }
    }
    int tot = r0+r1+r2+r3;
    lds[t] = tot; __syncthreads();
    for (int off=1; off<256; off<<=1){
      int add = (t>=off)?lds[t-off]:0;
      __syncthreads();
      lds[t] += add;
      __syncthreads();
    }
    int excl = lds[t] - tot;
    if (t==255) bsum[b] = lds[t];
    int run = excl;
    if (base+0<N){ rowptr[base+0]=run; run+=r0; }
    if (base+1<N){ rowptr[base+1]=run; run+=r1; }
    if (base+2<N){ rowptr[base+2]=run; run+=r2; }
    if (base+3<N){ rowptr[base+3]=run; }
    return;
  }

  // ---- GEMM1 (MFMA): h1 = x @ W1 -> fp16, + a_src1/a_dst1 ----
  _Float16* As = (_Float16*)smem;           // [64 rows][136 halves] (272 B stride)
  int n0 = (b - SB)*64;

  #pragma unroll
  for (int it=0; it<8; ++it){
    int c = it*256 + t;
    int row = c >> 5;
    int c4  = c & 31;
    int gr = n0 + row; if (gr > N-1) gr = N-1;
    float4 v = *(const float4*)(x + (size_t)gr*128 + c4*4);
    _Float16* dp = As + row*136 + c4*4;
    dp[0]=(_Float16)v.x; dp[1]=(_Float16)v.y; dp[2]=(_Float16)v.z; dp[3]=(_Float16)v.w;
  }
  __syncthreads();

  int wv = t>>6, lane = t&63;
  int m = lane&15, q = lane>>4;
  int r0w = wv*16;

  f16x8 afr[4];
  #pragma unroll
  for (int ks=0; ks<4; ++ks)
    afr[ks] = *(const f16x8*)((const char*)As + (r0w+m)*272 + ks*64 + q*16);

  f32x4 acc[16];
  #pragma unroll
  for (int ct=0; ct<16; ++ct) acc[ct] = (f32x4){0.f,0.f,0.f,0.f};

  const char* bbase = (const char*)W1t;
  #pragma unroll
  for (int ct=0; ct<16; ++ct){
    const char* bp = bbase + (ct*16 + m)*256 + q*16;
    f16x8 b0 = *(const f16x8*)(bp);
    f16x8 b1 = *(const f16x8*)(bp+64);
    f16x8 b2 = *(const f16x8*)(bp+128);
    f16x8 b3 = *(const f16x8*)(bp+192);
    acc[ct] = __builtin_amdgcn_mfma_f32_16x16x32_f16(afr[0], b0, acc[ct],0,0,0);
    acc[ct] = __builtin_amdgcn_mfma_f32_16x16x32_f16(afr[1], b1, acc[ct],0,0,0);
    acc[ct] = __builtin_amdgcn_mfma_f32_16x16x32_f16(afr[2], b2, acc[ct],0,0,0);
    acc[ct] = __builtin_amdgcn_mfma_f32_16x16x32_f16(afr[3], b3, acc[ct],0,0,0);
  }
  __syncthreads();

  _Float16* Hs = (_Float16*)smem;           // [64][264] halves, 528B stride
  #pragma unroll
  for (int ct=0; ct<16; ++ct){
    #pragma unroll
    for (int r=0; r<4; ++r)
      Hs[(size_t)(r0w + q*4 + r)*264 + ct*16 + m] = (_Float16)acc[ct][r];
  }
  __syncthreads();

  for (int r=0; r<16; ++r){
    int grow = n0 + r0w + r;
    if (grow < N){
      uint2 v = *(const uint2*)((const char*)Hs + (size_t)(r0w+r)*528 + lane*8);
      *(uint2*)((char*)h1 + (size_t)grow*512 + lane*8) = v;
    }
  }

  #pragma unroll
  for (int p=t; p<512; p+=256){
    int row = p>>3, hd = p&7;
    int grow = n0 + row;
    if (grow < N){
      const _Float16* hr = Hs + (size_t)row*264 + hd*32;
      float sa=0.f, sd=0.f;
      #pragma unroll
      for (int c=0; c<32; ++c){
        float hv = (float)hr[c];
        sa += hv * as1[hd*32+c];
        sd += hv * ad1[hd*32+c];
      }
      a_src1[(size_t)grow*8+hd] = sa;
      a_dst1[(size_t)grow*8+hd] = sd;
    }
  }
}

// ---------------- K3: scatter (LDS u16 cursors) + rowfin finalize ----------------
__global__ __launch_bounds__(256) void k_scatter3(const int* __restrict__ srcv,
    const int* __restrict__ dstv, const int* __restrict__ rowptr,
    const unsigned short* __restrict__ pu, const int* __restrict__ bsum,
    int* __restrict__ csr_src, int* __restrict__ rowfin,
    int E, int Etot, int chunk, int SB, int N)
{
  __shared__ unsigned int cur[NW];
  __shared__ int bpre[64];
  int b = blockIdx.x, t = threadIdx.x;
  for (int i=t; i<NW; i+=256) cur[i] = 0u;
  if (t==0){ int run=0; for (int j=0;j<SB;++j){ bpre[j]=run; run+=bsum[j]; } }
  __syncthreads();

  // finalize rowptr into rowfin (blocks 0..SB-1; reads local rowptr, writes rowfin)
  if (b < SB){
    int pref = bpre[b];
    int i = b*1024 + t*4;
    if (i+0 < N) rowfin[i+0] = rowptr[i+0] + pref;
    if (i+1 < N) rowfin[i+1] = rowptr[i+1] + pref;
    if (i+2 < N) rowfin[i+2] = rowptr[i+2] + pref;
    if (i+3 < N) rowfin[i+3] = rowptr[i+3] + pref;
    if (b==0 && t==0) rowfin[N] = Etot;
  }

  const unsigned short* pb = pu + (size_t)b*NBINS;
  int e0 = b*chunk, e1 = e0+chunk; if (e1 > Etot) e1 = Etot;
  int e = e0 + t;
  for (; e + 768 < e1; e += 1024){
    int ea=e, eb=e+256, ec=e+512, ed=e+768;
    int d0,s0,d1,s1,d2,s2,d3,s3;
    if (ea<E){ d0=dstv[ea]; s0=srcv[ea]; } else { d0=ea-E; s0=d0; }
    if (eb<E){ d1=dstv[eb]; s1=srcv[eb]; } else { d1=eb-E; s1=d1; }
    if (ec<E){ d2=dstv[ec]; s2=srcv[ec]; } else { d2=ec-E; s2=d2; }
    if (ed<E){ d3=dstv[ed]; s3=srcv[ed]; } else { d3=ed-E; s3=d3; }
    int base0 = rowptr[d0] + bpre[d0>>10] + (int)pb[d0];
    int base1 = rowptr[d1] + bpre[d1>>10] + (int)pb[d1];
    int base2 = rowptr[d2] + bpre[d2>>10] + (int)pb[d2];
    int base3 = rowptr[d3] + bpre[d3>>10] + (int)pb[d3];
    unsigned int o0 = atomicAdd(&cur[d0>>1], (d0&1)?65536u:1u);
    csr_src[base0 + ((d0&1)?(int)(o0>>16):(int)(o0&0xffff))] = s0;
    unsigned int o1 = atomicAdd(&cur[d1>>1], (d1&1)?65536u:1u);
    csr_src[base1 + ((d1&1)?(int)(o1>>16):(int)(o1&0xffff))] = s1;
    unsigned int o2 = atomicAdd(&cur[d2>>1], (d2&1)?65536u:1u);
    csr_src[base2 + ((d2&1)?(int)(o2>>16):(int)(o2&0xffff))] = s2;
    unsigned int o3 = atomicAdd(&cur[d3>>1], (d3&1)?65536u:1u);
    csr_src[base3 + ((d3&1)?(int)(o3>>16):(int)(o3&0xffff))] = s3;
  }
  for (; e < e1; e += 256){
    int d,s;
    if (e<E){ d=dstv[e]; s=srcv[e]; } else { d=e-E; s=d; }
    int base = rowptr[d] + bpre[d>>10] + (int)pb[d];
    unsigned int o = atomicAdd(&cur[d>>1], (d&1)?65536u:1u);
    csr_src[base + ((d&1)?(int)(o>>16):(int)(o&0xffff))] = s;
  }
}

// ---------------- K4: Layer-1 aggregation (wave/dst, x8/x4/x1 unroll) ----------------
__global__ __launch_bounds__(256) void k_agg1(const __half* __restrict__ h1,
    const float* __restrict__ a_src1, const float* __restrict__ a_dst1,
    const int* __restrict__ rowfin, const int* __restrict__ csr_src,
    const float* __restrict__ bias1, _Float16* __restrict__ h2f, int N)
{
  int wave = (blockIdx.x*blockDim.x + threadIdx.x) >> 6;
  if (wave >= N) return;
  int lane = threadIdx.x & 63;
  int head = lane >> 3;
  float ad = a_dst1[(size_t)wave*8 + head];
  int beg = rowfin[wave], end = rowfin[wave+1];
  float4 acc = make_float4(0.f,0.f,0.f,0.f);
  float wsum = 0.f;
  int i = beg;
  for (; i+8 <= end; i+=8){
    int s[8]; float e[8]; uint2 p[8];
    #pragma unroll
    for (int j=0;j<8;++j) s[j]=csr_src[i+j];
    #pragma unroll
    for (int j=0;j<8;++j){
      e[j]=a_src1[(size_t)s[j]*8+head];
      p[j]=*(const uint2*)((const char*)h1 + (size_t)s[j]*512 + lane*8);
    }
    #pragma unroll
    for (int j=0;j<8;++j){
      float w=__expf(lrelu(e[j]+ad));
      wsum += w;
      const __half2* qq=(const __half2*)&p[j];
      float2 f0=__half22float2(qq[0]), f1=__half22float2(qq[1]);
      acc.x += w*f0.x; acc.y += w*f0.y; acc.z += w*f1.x; acc.w += w*f1.y;
    }
  }
  for (; i+4 <= end; i+=4){
    int s[4]; float e[4]; uint2 p[4];
    #pragma unroll
    for (int j=0;j<4;++j) s[j]=csr_src[i+j];
    #pragma unroll
    for (int j=0;j<4;++j){
      e[j]=a_src1[(size_t)s[j]*8+head];
      p[j]=*(const uint2*)((const char*)h1 + (size_t)s[j]*512 + lane*8);
    }
    #pragma unroll
    for (int j=0;j<4;++j){
      float w=__expf(lrelu(e[j]+ad));
      wsum += w;
      const __half2* qq=(const __half2*)&p[j];
      float2 f0=__half22float2(qq[0]), f1=__half22float2(qq[1]);
      acc.x += w*f0.x; acc.y += w*f0.y; acc.z += w*f1.x; acc.w += w*f1.y;
    }
  }
  for (; i<end; ++i){
    int s = csr_src[i];
    float w = __expf(lrelu(a_src1[(size_t)s*8+head] + ad));
    wsum += w;
    uint2 p = *(const uint2*)((const char*)h1 + (size_t)s*512 + lane*8);
    const __half2* qq=(const __half2*)&p;
    float2 f0=__half22float2(qq[0]), f1=__half22float2(qq[1]);
    acc.x += w*f0.x; acc.y += w*f0.y; acc.z += w*f1.x; acc.w += w*f1.y;
  }
  float dinv = 1.f/(wsum + 1e-16f);
  const float4 bv = *(const float4*)(bias1 + lane*4);
  float4 o;
  o.x = acc.x*dinv + bv.x;
  o.y = acc.y*dinv + bv.y;
  o.z = acc.z*dinv + bv.z;
  o.w = acc.w*dinv + bv.w;
  o.x = o.x > 0.f ? o.x : __expf(o.x)-1.f;
  o.y = o.y > 0.f ? o.y : __expf(o.y)-1.f;
  o.z = o.z > 0.f ? o.z : __expf(o.z)-1.f;
  o.w = o.w > 0.f ? o.w : __expf(o.w)-1.f;
  f16x4 ov = { (_Float16)o.x, (_Float16)o.y, (_Float16)o.z, (_Float16)o.w };
  *(f16x4*)(h2f + (size_t)wave*256 + lane*4) = ov;
}

// ---------------- K5: GEMM2 (MFMA): hb = h2f @ W2, + a_src2/a_dst2 ----------------
__global__ __launch_bounds__(256) void k_gemm2(const _Float16* __restrict__ h2f,
    const _Float16* __restrict__ W2t, const float* __restrict__ as2, const float* __restrict__ ad2,
    float* __restrict__ hb, float* __restrict__ a_src2, float* __restrict__ a_dst2, int N)
{
  int t = threadIdx.x, wv = t>>6, lane = t&63;
  int col = lane&15, q = lane>>4;
  int n0 = blockIdx.x*64 + wv*16;
  int am = n0 + col; if (am > N-1) am = N-1;

  const _Float16* arow = h2f + (size_t)am*256 + q*8;
  const _Float16* brow = W2t + (size_t)col*256 + q*8;
  f32x4 acc = (f32x4){0.f,0.f,0.f,0.f};
  #pragma unroll
  for (int ks=0; ks<8; ++ks){
    f16x8 a = *(const f16x8*)(arow + ks*32);
    f16x8 b = *(const f16x8*)(brow + ks*32);
    acc = __builtin_amdgcn_mfma_f32_16x16x32_f16(a, b, acc, 0,0,0);
  }

  float vs = as2[col], vd = ad2[col];
  #pragma unroll
  for (int r=0; r<4; ++r){
    int n = n0 + q*4 + r;
    float v = acc[r];
    float pa = v*vs, pd = v*vd;
    #pragma unroll
    for (int msk=8; msk>=1; msk>>=1){ pa += __shfl_xor(pa,msk); pd += __shfl_xor(pd,msk); }
    if (n < N){
      hb[(size_t)n*16 + col] = v;
      if (col==0){ a_src2[n] = pa; a_dst2[n] = pd; }
    }
  }
}

// ---------------- K6: Layer-2 aggregation: wave per dst, 4 edge-groups x 16 ch ----------------
__global__ __launch_bounds__(256) void k_agg2(const float* __restrict__ hb,
    const float* __restrict__ a_src2, const float* __restrict__ a_dst2,
    const int* __restrict__ rowfin, const int* __restrict__ csr_src,
    const float* __restrict__ bias2, float* __restrict__ out, int N)
{
  int wave = (blockIdx.x*blockDim.x + threadIdx.x) >> 6;
  if (wave >= N) return;
  int lane = threadIdx.x & 63;
  int eg   = lane >> 4;
  int ch   = lane & 15;
  float ad = a_dst2[wave];
  int beg = rowfin[wave], end = rowfin[wave+1];
  float acc = 0.f, wsum = 0.f;
  int i = beg + eg;
  for (; i+4 < end; i+=8){
    int s0 = csr_src[i], s1 = csr_src[i+4];
    float e0 = a_src2[s0], e1 = a_src2[s1];
    float h0 = hb[(size_t)s0*16 + ch], h1v = hb[(size_t)s1*16 + ch];
    float w0 = __expf(lrelu(e0 + ad)), w1 = __expf(lrelu(e1 + ad));
    wsum += w0 + w1;
    acc += w0*h0 + w1*h1v;
  }
  for (; i<end; i+=4){
    int s = csr_src[i];
    float w = __expf(lrelu(a_src2[s] + ad));
    wsum += w;
    acc += w * hb[(size_t)s*16 + ch];
  }
  acc  += __shfl_xor(acc, 16);  acc  += __shfl_xor(acc, 32);
  wsum += __shfl_xor(wsum, 16); wsum += __shfl_xor(wsum, 32);
  if (eg == 0)
    out[(size_t)wave*16 + ch] = acc/(wsum + 1e-16f) + bias2[ch];
}

extern "C" void kernel_launch(void* const* d_in, const int* in_sizes, int n_in,
                              void* d_out, int out_size, void* d_ws, size_t ws_size,
                              hipStream_t stream)
{
  const float* x   = (const float*)d_in[0];
  const int*   ei  = (const int*)  d_in[1];
  const float* W1  = (const float*)d_in[2];
  const float* as1 = (const float*)d_in[3];
  const float* ad1 = (const float*)d_in[4];
  const float* b1  = (const float*)d_in[5];
  const float* W2  = (const float*)d_in[6];
  const float* as2 = (const float*)d_in[7];
  const float* ad2 = (const float*)d_in[8];
  const float* b2  = (const float*)d_in[9];
  float* out = (float*)d_out;

  const int N    = in_sizes[0] / 128;       // 50000
  const int E    = in_sizes[1] / 2;         // 800000
  const int Etot = E + N;
  const int* srcv = ei;
  const int* dstv = ei + E;
  const int chunk = (Etot + NB - 1) / NB;   // 13282 < 65536 (u16-field safe)
  const int SB    = (N + 1023) / 1024;      // 49 scan blocks
  const int TN    = (N + 63) / 64;          // 782 gemm1 tiles

  char* p = (char*)d_ws;
  auto alloc = [&](size_t bytes)->void* {
    void* r = (void*)p;
    p += (bytes + 255) & ~((size_t)255);
    return r;
  };
  _Float16* h1   = (_Float16*)alloc((size_t)N*256*sizeof(_Float16));   // node-major [N][256]
  _Float16* W1t  = (_Float16*)alloc((size_t)256*128*sizeof(_Float16));
  _Float16* h2f  = (_Float16*)alloc((size_t)N*256*sizeof(_Float16));
  _Float16* W2t  = (_Float16*)alloc((size_t)16*256*sizeof(_Float16));
  float* a_src1  = (float*)alloc((size_t)N*8*sizeof(float));
  float* a_dst1  = (float*)alloc((size_t)N*8*sizeof(float));
  float* hb      = (float*)alloc((size_t)N*16*sizeof(float));
  float* a_src2  = (float*)alloc((size_t)N*sizeof(float));
  float* a_dst2  = (float*)alloc((size_t)N*sizeof(float));
  int*   rowptr  = (int*)alloc((size_t)(N+1)*sizeof(int));
  int*   rowfin  = (int*)alloc((size_t)(N+1)*sizeof(int));
  int*   bsum    = (int*)alloc(256*sizeof(int));
  unsigned int* partial = (unsigned int*)alloc((size_t)NB*NW*sizeof(unsigned int));
  int*   csr_src = (int*)alloc((size_t)Etot*sizeof(int));

  // K1: histogram (packed u16) + weight prep
  k_histW<<<dim3(NB+129), dim3(256), 0, stream>>>(dstv, partial, E, Etot, chunk,
                                                  W1, W1t, W2, W2t);
  // K2: scanAB (blocks 0..SB-1) + gemm1 (blocks SB..SB+TN-1) -- independent halves
  k_g1scan<<<dim3(SB + TN), dim3(256), 0, stream>>>(x, W1t, as1, ad1, h1,
      a_src1, a_dst1, (unsigned long long*)partial, rowptr, bsum, N, SB);
  // K3: scatter + rowfin finalize
  k_scatter3<<<dim3(NB), dim3(256), 0, stream>>>(srcv, dstv, rowptr,
      (const unsigned short*)partial, bsum, csr_src, rowfin, E, Etot, chunk, SB, N);
  // K4: agg1
  k_agg1<<<dim3((N + 3)/4), dim3(256), 0, stream>>>((const __half*)h1, a_src1, a_dst1,
      rowfin, csr_src, b1, h2f, N);
  // K5: gemm2
  k_gemm2<<<dim3((N + 63)/64), dim3(256), 0, stream>>>(h2f, W2t, as2, ad2, hb, a_src2, a_dst2, N);
  // K6: agg2
  k_agg2<<<dim3((N + 3)/4), dim3(256), 0, stream>>>(hb, a_src2, a_dst2, rowfin, csr_src, b2, out, N);
}

// Round 12
// 271.332 us; speedup vs baseline: 1.3865x; 1.0840x over previous
//
#include <hip/hip_runtime.h>
#include <hip/hip_fp16.h>
#include <math.h>

// 2-layer GAT. N=50000, E=800000 (+N self loops), F=128, H=8, C=32, NCLS=16.
// R12: NB 64 -> 256. R11 ledger showed histW+scatter3 carrying ~150us: they ran
// 64 blocks x 100KB LDS = 1 blk/CU on only 64/256 CUs, 1 wave/SIMD, 52 serial
// global-load+LDS-atomic iterations. 256 blocks -> all CUs, 4x shorter loops.
// Cost: partial = 25.6MB, scanAB sums 256 partials (hidden under gemm1 in K2).
//   K1 histW | K2 scanAB+gemm1 | K3 scatter3+rowfin | K4 agg1 | K5 gemm2 | K6 agg2

#define NB    256
#define NBINS 50000
#define NW    25000

typedef _Float16 f16x8 __attribute__((ext_vector_type(8)));
typedef _Float16 f16x4 __attribute__((ext_vector_type(4)));
typedef float    f32x4 __attribute__((ext_vector_type(4)));

__device__ __forceinline__ float lrelu(float v){ return v > 0.f ? v : 0.2f*v; }

// ---------------- K1: hist (packed u16) + weight prep ----------------
__global__ __launch_bounds__(256) void k_histW(const int* __restrict__ dstv,
    unsigned int* __restrict__ partial, int E, int Etot, int chunk,
    const float* __restrict__ W1, _Float16* __restrict__ W1t,
    const float* __restrict__ W2, _Float16* __restrict__ W2t)
{
  int b = blockIdx.x, t = threadIdx.x;
  if (b >= NB){
    int b2 = b - NB;
    if (b2 < 128){
      W1t[t*128 + b2] = (_Float16)W1[b2*256 + t];
    } else {
      for (int i=t; i<4096; i+=256){ int k=i&255, j=i>>8; W2t[j*256+k] = (_Float16)W2[k*16+j]; }
    }
    return;
  }
  __shared__ unsigned int cnt[NW];
  for (int i=t; i<NW; i+=256) cnt[i] = 0u;
  __syncthreads();
  int e0 = b*chunk, e1 = e0+chunk; if (e1 > Etot) e1 = Etot;
  int e = e0 + t;
  for (; e + 768 < e1; e += 1024){
    int ea=e, eb=e+256, ec=e+512, ed=e+768;
    int d0 = (ea<E)?dstv[ea]:(ea-E);
    int d1 = (eb<E)?dstv[eb]:(eb-E);
    int d2 = (ec<E)?dstv[ec]:(ec-E);
    int d3 = (ed<E)?dstv[ed]:(ed-E);
    atomicAdd(&cnt[d0>>1], (d0&1)?65536u:1u);
    atomicAdd(&cnt[d1>>1], (d1&1)?65536u:1u);
    atomicAdd(&cnt[d2>>1], (d2&1)?65536u:1u);
    atomicAdd(&cnt[d3>>1], (d3&1)?65536u:1u);
  }
  for (; e < e1; e += 256){
    int d = (e<E)?dstv[e]:(e-E);
    atomicAdd(&cnt[d>>1], (d&1)?65536u:1u);
  }
  __syncthreads();
  unsigned int* dp = partial + (size_t)b*NW;
  for (int i=t; i<NW; i+=256) dp[i] = cnt[i];
}

// ---------------- K2: scanAB (blocks 0..SB-1) + GEMM1 tiles (blocks SB..) ----------------
__global__ __launch_bounds__(256) void k_g1scan(const float* __restrict__ x,
    const _Float16* __restrict__ W1t, const float* __restrict__ as1,
    const float* __restrict__ ad1, _Float16* __restrict__ h1,
    float* __restrict__ a_src1, float* __restrict__ a_dst1,
    unsigned long long* __restrict__ partial, int* __restrict__ rowptr,
    int* __restrict__ bsum, int N, int SB)
{
  __shared__ char smem[33792];
  int t = threadIdx.x;
  int b = blockIdx.x;

  if (b < SB){
    // ---- scanAB: per-bin partial prefix (u64 over 4 bins) + block scan ----
    int* lds = (int*)smem;
    int base = b*1024 + t*4;
    int r0=0, r1=0, r2=0, r3=0;
    if (base < N){
      unsigned long long* P = partial + (base >> 2);
      #pragma unroll 8
      for (int bb=0; bb<NB; ++bb){
        unsigned long long v = P[(size_t)bb*12500];
        unsigned long long pref =  (unsigned long long)(r0 & 0xffff)
          | ((unsigned long long)(r1 & 0xffff) << 16)
          | ((unsigned long long)(r2 & 0xffff) << 32)
          | ((unsigned long long)(r3 & 0xffff) << 48);
        P[(size_t)bb*12500] = pref;
        r0 += (int)( v        & 0xffff);
        r1 += (int)((v >> 16) & 0xffff);
        r2 += (int)((v >> 32) & 0xffff);
        r3 += (int)((v >> 48) & 0xffff);
      }
    }
    int tot = r0+r1+r2+r3;
    lds[t] = tot; __syncthreads();
    for (int off=1; off<256; off<<=1){
      int add = (t>=off)?lds[t-off]:0;
      __syncthreads();
      lds[t] += add;
      __syncthreads();
    }
    int excl = lds[t] - tot;
    if (t==255) bsum[b] = lds[t];
    int run = excl;
    if (base+0<N){ rowptr[base+0]=run; run+=r0; }
    if (base+1<N){ rowptr[base+1]=run; run+=r1; }
    if (base+2<N){ rowptr[base+2]=run; run+=r2; }
    if (base+3<N){ rowptr[base+3]=run; }
    return;
  }

  // ---- GEMM1 (MFMA): h1 = x @ W1 -> fp16, + a_src1/a_dst1 ----
  _Float16* As = (_Float16*)smem;           // [64 rows][136 halves] (272 B stride)
  int n0 = (b - SB)*64;

  #pragma unroll
  for (int it=0; it<8; ++it){
    int c = it*256 + t;
    int row = c >> 5;
    int c4  = c & 31;
    int gr = n0 + row; if (gr > N-1) gr = N-1;
    float4 v = *(const float4*)(x + (size_t)gr*128 + c4*4);
    _Float16* dp = As + row*136 + c4*4;
    dp[0]=(_Float16)v.x; dp[1]=(_Float16)v.y; dp[2]=(_Float16)v.z; dp[3]=(_Float16)v.w;
  }
  __syncthreads();

  int wv = t>>6, lane = t&63;
  int m = lane&15, q = lane>>4;
  int r0w = wv*16;

  f16x8 afr[4];
  #pragma unroll
  for (int ks=0; ks<4; ++ks)
    afr[ks] = *(const f16x8*)((const char*)As + (r0w+m)*272 + ks*64 + q*16);

  f32x4 acc[16];
  #pragma unroll
  for (int ct=0; ct<16; ++ct) acc[ct] = (f32x4){0.f,0.f,0.f,0.f};

  const char* bbase = (const char*)W1t;
  #pragma unroll
  for (int ct=0; ct<16; ++ct){
    const char* bp = bbase + (ct*16 + m)*256 + q*16;
    f16x8 b0 = *(const f16x8*)(bp);
    f16x8 b1 = *(const f16x8*)(bp+64);
    f16x8 b2 = *(const f16x8*)(bp+128);
    f16x8 b3 = *(const f16x8*)(bp+192);
    acc[ct] = __builtin_amdgcn_mfma_f32_16x16x32_f16(afr[0], b0, acc[ct],0,0,0);
    acc[ct] = __builtin_amdgcn_mfma_f32_16x16x32_f16(afr[1], b1, acc[ct],0,0,0);
    acc[ct] = __builtin_amdgcn_mfma_f32_16x16x32_f16(afr[2], b2, acc[ct],0,0,0);
    acc[ct] = __builtin_amdgcn_mfma_f32_16x16x32_f16(afr[3], b3, acc[ct],0,0,0);
  }
  __syncthreads();

  _Float16* Hs = (_Float16*)smem;           // [64][264] halves, 528B stride
  #pragma unroll
  for (int ct=0; ct<16; ++ct){
    #pragma unroll
    for (int r=0; r<4; ++r)
      Hs[(size_t)(r0w + q*4 + r)*264 + ct*16 + m] = (_Float16)acc[ct][r];
  }
  __syncthreads();

  for (int r=0; r<16; ++r){
    int grow = n0 + r0w + r;
    if (grow < N){
      uint2 v = *(const uint2*)((const char*)Hs + (size_t)(r0w+r)*528 + lane*8);
      *(uint2*)((char*)h1 + (size_t)grow*512 + lane*8) = v;
    }
  }

  #pragma unroll
  for (int p=t; p<512; p+=256){
    int row = p>>3, hd = p&7;
    int grow = n0 + row;
    if (grow < N){
      const _Float16* hr = Hs + (size_t)row*264 + hd*32;
      float sa=0.f, sd=0.f;
      #pragma unroll
      for (int c=0; c<32; ++c){
        float hv = (float)hr[c];
        sa += hv * as1[hd*32+c];
        sd += hv * ad1[hd*32+c];
      }
      a_src1[(size_t)grow*8+hd] = sa;
      a_dst1[(size_t)grow*8+hd] = sd;
    }
  }
}

// ---------------- K3: scatter (LDS u16 cursors) + rowfin finalize ----------------
__global__ __launch_bounds__(256) void k_scatter3(const int* __restrict__ srcv,
    const int* __restrict__ dstv, const int* __restrict__ rowptr,
    const unsigned short* __restrict__ pu, const int* __restrict__ bsum,
    int* __restrict__ csr_src, int* __restrict__ rowfin,
    int E, int Etot, int chunk, int SB, int N)
{
  __shared__ unsigned int cur[NW];
  __shared__ int bpre[64];
  int b = blockIdx.x, t = threadIdx.x;
  for (int i=t; i<NW; i+=256) cur[i] = 0u;
  if (t==0){ int run=0; for (int j=0;j<SB;++j){ bpre[j]=run; run+=bsum[j]; } }
  __syncthreads();

  // finalize rowptr into rowfin (blocks 0..SB-1; reads local rowptr, writes rowfin)
  if (b < SB){
    int pref = bpre[b];
    int i = b*1024 + t*4;
    if (i+0 < N) rowfin[i+0] = rowptr[i+0] + pref;
    if (i+1 < N) rowfin[i+1] = rowptr[i+1] + pref;
    if (i+2 < N) rowfin[i+2] = rowptr[i+2] + pref;
    if (i+3 < N) rowfin[i+3] = rowptr[i+3] + pref;
    if (b==0 && t==0) rowfin[N] = Etot;
  }

  const unsigned short* pb = pu + (size_t)b*NBINS;
  int e0 = b*chunk, e1 = e0+chunk; if (e1 > Etot) e1 = Etot;
  int e = e0 + t;
  for (; e + 768 < e1; e += 1024){
    int ea=e, eb=e+256, ec=e+512, ed=e+768;
    int d0,s0,d1,s1,d2,s2,d3,s3;
    if (ea<E){ d0=dstv[ea]; s0=srcv[ea]; } else { d0=ea-E; s0=d0; }
    if (eb<E){ d1=dstv[eb]; s1=srcv[eb]; } else { d1=eb-E; s1=d1; }
    if (ec<E){ d2=dstv[ec]; s2=srcv[ec]; } else { d2=ec-E; s2=d2; }
    if (ed<E){ d3=dstv[ed]; s3=srcv[ed]; } else { d3=ed-E; s3=d3; }
    int base0 = rowptr[d0] + bpre[d0>>10] + (int)pb[d0];
    int base1 = rowptr[d1] + bpre[d1>>10] + (int)pb[d1];
    int base2 = rowptr[d2] + bpre[d2>>10] + (int)pb[d2];
    int base3 = rowptr[d3] + bpre[d3>>10] + (int)pb[d3];
    unsigned int o0 = atomicAdd(&cur[d0>>1], (d0&1)?65536u:1u);
    csr_src[base0 + ((d0&1)?(int)(o0>>16):(int)(o0&0xffff))] = s0;
    unsigned int o1 = atomicAdd(&cur[d1>>1], (d1&1)?65536u:1u);
    csr_src[base1 + ((d1&1)?(int)(o1>>16):(int)(o1&0xffff))] = s1;
    unsigned int o2 = atomicAdd(&cur[d2>>1], (d2&1)?65536u:1u);
    csr_src[base2 + ((d2&1)?(int)(o2>>16):(int)(o2&0xffff))] = s2;
    unsigned int o3 = atomicAdd(&cur[d3>>1], (d3&1)?65536u:1u);
    csr_src[base3 + ((d3&1)?(int)(o3>>16):(int)(o3&0xffff))] = s3;
  }
  for (; e < e1; e += 256){
    int d,s;
    if (e<E){ d=dstv[e]; s=srcv[e]; } else { d=e-E; s=d; }
    int base = rowptr[d] + bpre[d>>10] + (int)pb[d];
    unsigned int o = atomicAdd(&cur[d>>1], (d&1)?65536u:1u);
    csr_src[base + ((d&1)?(int)(o>>16):(int)(o&0xffff))] = s;
  }
}

// ---------------- K4: Layer-1 aggregation (wave/dst, x8/x4/x1 unroll) ----------------
__global__ __launch_bounds__(256) void k_agg1(const __half* __restrict__ h1,
    const float* __restrict__ a_src1, const float* __restrict__ a_dst1,
    const int* __restrict__ rowfin, const int* __restrict__ csr_src,
    const float* __restrict__ bias1, _Float16* __restrict__ h2f, int N)
{
  int wave = (blockIdx.x*blockDim.x + threadIdx.x) >> 6;
  if (wave >= N) return;
  int lane = threadIdx.x & 63;
  int head = lane >> 3;
  float ad = a_dst1[(size_t)wave*8 + head];
  int beg = rowfin[wave], end = rowfin[wave+1];
  float4 acc = make_float4(0.f,0.f,0.f,0.f);
  float wsum = 0.f;
  int i = beg;
  for (; i+8 <= end; i+=8){
    int s[8]; float e[8]; uint2 p[8];
    #pragma unroll
    for (int j=0;j<8;++j) s[j]=csr_src[i+j];
    #pragma unroll
    for (int j=0;j<8;++j){
      e[j]=a_src1[(size_t)s[j]*8+head];
      p[j]=*(const uint2*)((const char*)h1 + (size_t)s[j]*512 + lane*8);
    }
    #pragma unroll
    for (int j=0;j<8;++j){
      float w=__expf(lrelu(e[j]+ad));
      wsum += w;
      const __half2* qq=(const __half2*)&p[j];
      float2 f0=__half22float2(qq[0]), f1=__half22float2(qq[1]);
      acc.x += w*f0.x; acc.y += w*f0.y; acc.z += w*f1.x; acc.w += w*f1.y;
    }
  }
  for (; i+4 <= end; i+=4){
    int s[4]; float e[4]; uint2 p[4];
    #pragma unroll
    for (int j=0;j<4;++j) s[j]=csr_src[i+j];
    #pragma unroll
    for (int j=0;j<4;++j){
      e[j]=a_src1[(size_t)s[j]*8+head];
      p[j]=*(const uint2*)((const char*)h1 + (size_t)s[j]*512 + lane*8);
    }
    #pragma unroll
    for (int j=0;j<4;++j){
      float w=__expf(lrelu(e[j]+ad));
      wsum += w;
      const __half2* qq=(const __half2*)&p[j];
      float2 f0=__half22float2(qq[0]), f1=__half22float2(qq[1]);
      acc.x += w*f0.x; acc.y += w*f0.y; acc.z += w*f1.x; acc.w += w*f1.y;
    }
  }
  for (; i<end; ++i){
    int s = csr_src[i];
    float w = __expf(lrelu(a_src1[(size_t)s*8+head] + ad));
    wsum += w;
    uint2 p = *(const uint2*)((const char*)h1 + (size_t)s*512 + lane*8);
    const __half2* qq=(const __half2*)&p;
    float2 f0=__half22float2(qq[0]), f1=__half22float2(qq[1]);
    acc.x += w*f0.x; acc.y += w*f0.y; acc.z += w*f1.x; acc.w += w*f1.y;
  }
  float dinv = 1.f/(wsum + 1e-16f);
  const float4 bv = *(const float4*)(bias1 + lane*4);
  float4 o;
  o.x = acc.x*dinv + bv.x;
  o.y = acc.y*dinv + bv.y;
  o.z = acc.z*dinv + bv.z;
  o.w = acc.w*dinv + bv.w;
  o.x = o.x > 0.f ? o.x : __expf(o.x)-1.f;
  o.y = o.y > 0.f ? o.y : __expf(o.y)-1.f;
  o.z = o.z > 0.f ? o.z : __expf(o.z)-1.f;
  o.w = o.w > 0.f ? o.w : __expf(o.w)-1.f;
  f16x4 ov = { (_Float16)o.x, (_Float16)o.y, (_Float16)o.z, (_Float16)o.w };
  *(f16x4*)(h2f + (size_t)wave*256 + lane*4) = ov;
}

// ---------------- K5: GEMM2 (MFMA): hb = h2f @ W2, + a_src2/a_dst2 ----------------
__global__ __launch_bounds__(256) void k_gemm2(const _Float16* __restrict__ h2f,
    const _Float16* __restrict__ W2t, const float* __restrict__ as2, const float* __restrict__ ad2,
    float* __restrict__ hb, float* __restrict__ a_src2, float* __restrict__ a_dst2, int N)
{
  int t = threadIdx.x, wv = t>>6, lane = t&63;
  int col = lane&15, q = lane>>4;
  int n0 = blockIdx.x*64 + wv*16;
  int am = n0 + col; if (am > N-1) am = N-1;

  const _Float16* arow = h2f + (size_t)am*256 + q*8;
  const _Float16* brow = W2t + (size_t)col*256 + q*8;
  f32x4 acc = (f32x4){0.f,0.f,0.f,0.f};
  #pragma unroll
  for (int ks=0; ks<8; ++ks){
    f16x8 a = *(const f16x8*)(arow + ks*32);
    f16x8 b = *(const f16x8*)(brow + ks*32);
    acc = __builtin_amdgcn_mfma_f32_16x16x32_f16(a, b, acc, 0,0,0);
  }

  float vs = as2[col], vd = ad2[col];
  #pragma unroll
  for (int r=0; r<4; ++r){
    int n = n0 + q*4 + r;
    float v = acc[r];
    float pa = v*vs, pd = v*vd;
    #pragma unroll
    for (int msk=8; msk>=1; msk>>=1){ pa += __shfl_xor(pa,msk); pd += __shfl_xor(pd,msk); }
    if (n < N){
      hb[(size_t)n*16 + col] = v;
      if (col==0){ a_src2[n] = pa; a_dst2[n] = pd; }
    }
  }
}

// ---------------- K6: Layer-2 aggregation: wave per dst, 4 edge-groups x 16 ch ----------------
__global__ __launch_bounds__(256) void k_agg2(const float* __restrict__ hb,
    const float* __restrict__ a_src2, const float* __restrict__ a_dst2,
    const int* __restrict__ rowfin, const int* __restrict__ csr_src,
    const float* __restrict__ bias2, float* __restrict__ out, int N)
{
  int wave = (blockIdx.x*blockDim.x + threadIdx.x) >> 6;
  if (wave >= N) return;
  int lane = threadIdx.x & 63;
  int eg   = lane >> 4;
  int ch   = lane & 15;
  float ad = a_dst2[wave];
  int beg = rowfin[wave], end = rowfin[wave+1];
  float acc = 0.f, wsum = 0.f;
  int i = beg + eg;
  for (; i+4 < end; i+=8){
    int s0 = csr_src[i], s1 = csr_src[i+4];
    float e0 = a_src2[s0], e1 = a_src2[s1];
    float h0 = hb[(size_t)s0*16 + ch], h1v = hb[(size_t)s1*16 + ch];
    float w0 = __expf(lrelu(e0 + ad)), w1 = __expf(lrelu(e1 + ad));
    wsum += w0 + w1;
    acc += w0*h0 + w1*h1v;
  }
  for (; i<end; i+=4){
    int s = csr_src[i];
    float w = __expf(lrelu(a_src2[s] + ad));
    wsum += w;
    acc += w * hb[(size_t)s*16 + ch];
  }
  acc  += __shfl_xor(acc, 16);  acc  += __shfl_xor(acc, 32);
  wsum += __shfl_xor(wsum, 16); wsum += __shfl_xor(wsum, 32);
  if (eg == 0)
    out[(size_t)wave*16 + ch] = acc/(wsum + 1e-16f) + bias2[ch];
}

extern "C" void kernel_launch(void* const* d_in, const int* in_sizes, int n_in,
                              void* d_out, int out_size, void* d_ws, size_t ws_size,
                              hipStream_t stream)
{
  const float* x   = (const float*)d_in[0];
  const int*   ei  = (const int*)  d_in[1];
  const float* W1  = (const float*)d_in[2];
  const float* as1 = (const float*)d_in[3];
  const float* ad1 = (const float*)d_in[4];
  const float* b1  = (const float*)d_in[5];
  const float* W2  = (const float*)d_in[6];
  const float* as2 = (const float*)d_in[7];
  const float* ad2 = (const float*)d_in[8];
  const float* b2  = (const float*)d_in[9];
  float* out = (float*)d_out;

  const int N    = in_sizes[0] / 128;       // 50000
  const int E    = in_sizes[1] / 2;         // 800000
  const int Etot = E + N;
  const int* srcv = ei;
  const int* dstv = ei + E;
  const int chunk = (Etot + NB - 1) / NB;   // 3321 < 65536 (u16-field safe)
  const int SB    = (N + 1023) / 1024;      // 49 scan blocks
  const int TN    = (N + 63) / 64;          // 782 gemm1 tiles

  char* p = (char*)d_ws;
  auto alloc = [&](size_t bytes)->void* {
    void* r = (void*)p;
    p += (bytes + 255) & ~((size_t)255);
    return r;
  };
  _Float16* h1   = (_Float16*)alloc((size_t)N*256*sizeof(_Float16));   // node-major [N][256]
  _Float16* W1t  = (_Float16*)alloc((size_t)256*128*sizeof(_Float16));
  _Float16* h2f  = (_Float16*)alloc((size_t)N*256*sizeof(_Float16));
  _Float16* W2t  = (_Float16*)alloc((size_t)16*256*sizeof(_Float16));
  float* a_src1  = (float*)alloc((size_t)N*8*sizeof(float));
  float* a_dst1  = (float*)alloc((size_t)N*8*sizeof(float));
  float* hb      = (float*)alloc((size_t)N*16*sizeof(float));
  float* a_src2  = (float*)alloc((size_t)N*sizeof(float));
  float* a_dst2  = (float*)alloc((size_t)N*sizeof(float));
  int*   rowptr  = (int*)alloc((size_t)(N+1)*sizeof(int));
  int*   rowfin  = (int*)alloc((size_t)(N+1)*sizeof(int));
  int*   bsum    = (int*)alloc(256*sizeof(int));
  unsigned int* partial = (unsigned int*)alloc((size_t)NB*NW*sizeof(unsigned int));
  int*   csr_src = (int*)alloc((size_t)Etot*sizeof(int));

  // K1: histogram (packed u16, 256 blocks) + weight prep
  k_histW<<<dim3(NB+129), dim3(256), 0, stream>>>(dstv, partial, E, Etot, chunk,
                                                  W1, W1t, W2, W2t);
  // K2: scanAB (blocks 0..SB-1) + gemm1 (blocks SB..SB+TN-1) -- independent halves
  k_g1scan<<<dim3(SB + TN), dim3(256), 0, stream>>>(x, W1t, as1, ad1, h1,
      a_src1, a_dst1, (unsigned long long*)partial, rowptr, bsum, N, SB);
  // K3: scatter + rowfin finalize
  k_scatter3<<<dim3(NB), dim3(256), 0, stream>>>(srcv, dstv, rowptr,
      (const unsigned short*)partial, bsum, csr_src, rowfin, E, Etot, chunk, SB, N);
  // K4: agg1
  k_agg1<<<dim3((N + 3)/4), dim3(256), 0, stream>>>((const __half*)h1, a_src1, a_dst1,
      rowfin, csr_src, b1, h2f, N);
  // K5: gemm2
  k_gemm2<<<dim3((N + 63)/64), dim3(256), 0, stream>>>(h2f, W2t, as2, ad2, hb, a_src2, a_dst2, N);
  // K6: agg2
  k_agg2<<<dim3((N + 3)/4), dim3(256), 0, stream>>>(hb, a_src2, a_dst2, rowfin, csr_src, b2, out, N);
}

// Round 13
// 269.789 us; speedup vs baseline: 1.3944x; 1.0057x over previous
//
#include <hip/hip_runtime.h>
#include <hip/hip_fp16.h>
#include <math.h>

// 2-layer GAT. N=50000, E=800000 (+N self loops), F=128, H=8, C=32, NCLS=16.
// R13: (a) hist/scatter 2-D decomposition: 128 edge-chunks x 2 bin-halves =
// 256 blocks, 25000 bins (50KB LDS -> 2 blk/CU) per block. Fixed LDS loops
// 98+98 -> 49+49 iters; partial halves to 12.8MB; edges read twice (coalesced,
// cheap). (b) hb stored fp16 (only consumer agg2): halves gemm2 store +
// agg2 per-edge gather.
//   K1 histW | K2 scanAB+gemm1 | K3 scatter3+rowfin | K4 agg1 | K5 gemm2 | K6 agg2

#define NC    128          // edge chunks
#define NBK   256          // hist/scatter blocks = NC * 2 halves
#define NBINS 50000
#define HBINS 25000        // bins per half
#define NWH   12500        // packed u32 words per half (2 bins each)

typedef _Float16 f16x8 __attribute__((ext_vector_type(8)));
typedef _Float16 f16x4 __attribute__((ext_vector_type(4)));
typedef float    f32x4 __attribute__((ext_vector_type(4)));

__device__ __forceinline__ float lrelu(float v){ return v > 0.f ? v : 0.2f*v; }

// ---------------- K1: hist (packed u16, chunk x half) + weight prep ----------------
// partial layout: u16[chunk c][bin g] -> u32 word index c*25000 + (g>>1)
__global__ __launch_bounds__(256) void k_histW(const int* __restrict__ dstv,
    unsigned int* __restrict__ partial, int E, int Etot, int chunk,
    const float* __restrict__ W1, _Float16* __restrict__ W1t,
    const float* __restrict__ W2, _Float16* __restrict__ W2t)
{
  int b = blockIdx.x, t = threadIdx.x;
  if (b >= NBK){
    int b2 = b - NBK;
    if (b2 < 128){
      W1t[t*128 + b2] = (_Float16)W1[b2*256 + t];
    } else {
      for (int i=t; i<4096; i+=256){ int k=i&255, j=i>>8; W2t[j*256+k] = (_Float16)W2[k*16+j]; }
    }
    return;
  }
  __shared__ unsigned int cnt[NWH];         // 50 KB -> 2 blocks/CU
  int c = b >> 1, half = b & 1, lo = half*HBINS;
  for (int i=t; i<NWH; i+=256) cnt[i] = 0u;
  __syncthreads();
  int e0 = c*chunk, e1 = e0+chunk; if (e1 > Etot) e1 = Etot;
  int e = e0 + t;
  for (; e + 768 < e1; e += 1024){
    int ea=e, eb=e+256, ec=e+512, ed=e+768;
    int d0 = (ea<E)?dstv[ea]:(ea-E);
    int d1 = (eb<E)?dstv[eb]:(eb-E);
    int d2 = (ec<E)?dstv[ec]:(ec-E);
    int d3 = (ed<E)?dstv[ed]:(ed-E);
    int r0=d0-lo, r1=d1-lo, r2=d2-lo, r3=d3-lo;
    if (r0>=0 && r0<HBINS) atomicAdd(&cnt[r0>>1], (r0&1)?65536u:1u);
    if (r1>=0 && r1<HBINS) atomicAdd(&cnt[r1>>1], (r1&1)?65536u:1u);
    if (r2>=0 && r2<HBINS) atomicAdd(&cnt[r2>>1], (r2&1)?65536u:1u);
    if (r3>=0 && r3<HBINS) atomicAdd(&cnt[r3>>1], (r3&1)?65536u:1u);
  }
  for (; e < e1; e += 256){
    int d = (e<E)?dstv[e]:(e-E);
    int r = d - lo;
    if (r>=0 && r<HBINS) atomicAdd(&cnt[r>>1], (r&1)?65536u:1u);
  }
  __syncthreads();
  unsigned int* dp = partial + (size_t)c*HBINS + (size_t)half*NWH;  // c*25000 + half*12500
  for (int i=t; i<NWH; i+=256) dp[i] = cnt[i];
}

// ---------------- K2: scanAB (blocks 0..SB-1) + GEMM1 tiles (blocks SB..) ----------------
__global__ __launch_bounds__(256) void k_g1scan(const float* __restrict__ x,
    const _Float16* __restrict__ W1t, const float* __restrict__ as1,
    const float* __restrict__ ad1, _Float16* __restrict__ h1,
    float* __restrict__ a_src1, float* __restrict__ a_dst1,
    unsigned long long* __restrict__ partial, int* __restrict__ rowptr,
    int* __restrict__ bsum, int N, int SB)
{
  __shared__ char smem[33792];
  int t = threadIdx.x;
  int b = blockIdx.x;

  if (b < SB){
    // ---- scanAB: per-bin chunk prefix (u64 = 4 bins) + block scan ----
    int* lds = (int*)smem;
    int base = b*1024 + t*4;
    int r0=0, r1=0, r2=0, r3=0;
    if (base < N){
      unsigned long long* P = partial + (base >> 2);   // chunk stride = 50000 u16 = 12500 u64
      #pragma unroll 8
      for (int cc=0; cc<NC; ++cc){
        unsigned long long v = P[(size_t)cc*12500];
        unsigned long long pref =  (unsigned long long)(r0 & 0xffff)
          | ((unsigned long long)(r1 & 0xffff) << 16)
          | ((unsigned long long)(r2 & 0xffff) << 32)
          | ((unsigned long long)(r3 & 0xffff) << 48);
        P[(size_t)cc*12500] = pref;
        r0 += (int)( v        & 0xffff);
        r1 += (int)((v >> 16) & 0xffff);
        r2 += (int)((v >> 32) & 0xffff);
        r3 += (int)((v >> 48) & 0xffff);
      }
    }
    int tot = r0+r1+r2+r3;
    lds[t] = tot; __syncthreads();
    for (int off=1; off<256; off<<=1){
      int add = (t>=off)?lds[t-off]:0;
      __syncthreads();
      lds[t] += add;
      __syncthreads();
    }
    int excl = lds[t] - tot;
    if (t==255) bsum[b] = lds[t];
    int run = excl;
    if (base+0<N){ rowptr[base+0]=run; run+=r0; }
    if (base+1<N){ rowptr[base+1]=run; run+=r1; }
    if (base+2<N){ rowptr[base+2]=run; run+=r2; }
    if (base+3<N){ rowptr[base+3]=run; }
    return;
  }

  // ---- GEMM1 (MFMA): h1 = x @ W1 -> fp16, + a_src1/a_dst1 ----
  _Float16* As = (_Float16*)smem;           // [64 rows][136 halves] (272 B stride)
  int n0 = (b - SB)*64;

  #pragma unroll
  for (int it=0; it<8; ++it){
    int c = it*256 + t;
    int row = c >> 5;
    int c4  = c & 31;
    int gr = n0 + row; if (gr > N-1) gr = N-1;
    float4 v = *(const float4*)(x + (size_t)gr*128 + c4*4);
    _Float16* dp = As + row*136 + c4*4;
    dp[0]=(_Float16)v.x; dp[1]=(_Float16)v.y; dp[2]=(_Float16)v.z; dp[3]=(_Float16)v.w;
  }
  __syncthreads();

  int wv = t>>6, lane = t&63;
  int m = lane&15, q = lane>>4;
  int r0w = wv*16;

  f16x8 afr[4];
  #pragma unroll
  for (int ks=0; ks<4; ++ks)
    afr[ks] = *(const f16x8*)((const char*)As + (r0w+m)*272 + ks*64 + q*16);

  f32x4 acc[16];
  #pragma unroll
  for (int ct=0; ct<16; ++ct) acc[ct] = (f32x4){0.f,0.f,0.f,0.f};

  const char* bbase = (const char*)W1t;
  #pragma unroll
  for (int ct=0; ct<16; ++ct){
    const char* bp = bbase + (ct*16 + m)*256 + q*16;
    f16x8 b0 = *(const f16x8*)(bp);
    f16x8 b1 = *(const f16x8*)(bp+64);
    f16x8 b2 = *(const f16x8*)(bp+128);
    f16x8 b3 = *(const f16x8*)(bp+192);
    acc[ct] = __builtin_amdgcn_mfma_f32_16x16x32_f16(afr[0], b0, acc[ct],0,0,0);
    acc[ct] = __builtin_amdgcn_mfma_f32_16x16x32_f16(afr[1], b1, acc[ct],0,0,0);
    acc[ct] = __builtin_amdgcn_mfma_f32_16x16x32_f16(afr[2], b2, acc[ct],0,0,0);
    acc[ct] = __builtin_amdgcn_mfma_f32_16x16x32_f16(afr[3], b3, acc[ct],0,0,0);
  }
  __syncthreads();

  _Float16* Hs = (_Float16*)smem;           // [64][264] halves, 528B stride
  #pragma unroll
  for (int ct=0; ct<16; ++ct){
    #pragma unroll
    for (int r=0; r<4; ++r)
      Hs[(size_t)(r0w + q*4 + r)*264 + ct*16 + m] = (_Float16)acc[ct][r];
  }
  __syncthreads();

  for (int r=0; r<16; ++r){
    int grow = n0 + r0w + r;
    if (grow < N){
      uint2 v = *(const uint2*)((const char*)Hs + (size_t)(r0w+r)*528 + lane*8);
      *(uint2*)((char*)h1 + (size_t)grow*512 + lane*8) = v;
    }
  }

  #pragma unroll
  for (int p=t; p<512; p+=256){
    int row = p>>3, hd = p&7;
    int grow = n0 + row;
    if (grow < N){
      const _Float16* hr = Hs + (size_t)row*264 + hd*32;
      float sa=0.f, sd=0.f;
      #pragma unroll
      for (int c=0; c<32; ++c){
        float hv = (float)hr[c];
        sa += hv * as1[hd*32+c];
        sd += hv * ad1[hd*32+c];
      }
      a_src1[(size_t)grow*8+hd] = sa;
      a_dst1[(size_t)grow*8+hd] = sd;
    }
  }
}

// ---------------- K3: scatter (chunk x half, LDS u16 cursors) + rowfin finalize ----------------
__global__ __launch_bounds__(256) void k_scatter3(const int* __restrict__ srcv,
    const int* __restrict__ dstv, const int* __restrict__ rowptr,
    const unsigned short* __restrict__ pu, const int* __restrict__ bsum,
    int* __restrict__ csr_src, int* __restrict__ rowfin,
    int E, int Etot, int chunk, int SB, int N)
{
  __shared__ unsigned int cur[NWH];         // 50 KB -> 2 blocks/CU
  __shared__ int bpre[64];
  int b = blockIdx.x, t = threadIdx.x;
  int c = b >> 1, half = b & 1, lo = half*HBINS;
  for (int i=t; i<NWH; i+=256) cur[i] = 0u;
  if (t==0){ int run=0; for (int j=0;j<SB;++j){ bpre[j]=run; run+=bsum[j]; } }
  __syncthreads();

  // finalize rowptr into rowfin (blocks 0..SB-1)
  if (b < SB){
    int pref = bpre[b];
    int i = b*1024 + t*4;
    if (i+0 < N) rowfin[i+0] = rowptr[i+0] + pref;
    if (i+1 < N) rowfin[i+1] = rowptr[i+1] + pref;
    if (i+2 < N) rowfin[i+2] = rowptr[i+2] + pref;
    if (i+3 < N) rowfin[i+3] = rowptr[i+3] + pref;
    if (b==0 && t==0) rowfin[N] = Etot;
  }

  const unsigned short* pb = pu + (size_t)c*NBINS;   // u16[chunk c][bin g]
  int e0 = c*chunk, e1 = e0+chunk; if (e1 > Etot) e1 = Etot;
  int e = e0 + t;
  for (; e + 768 < e1; e += 1024){
    int ea=e, eb=e+256, ec=e+512, ed=e+768;
    int d0,s0,d1,s1,d2,s2,d3,s3;
    if (ea<E){ d0=dstv[ea]; s0=srcv[ea]; } else { d0=ea-E; s0=d0; }
    if (eb<E){ d1=dstv[eb]; s1=srcv[eb]; } else { d1=eb-E; s1=d1; }
    if (ec<E){ d2=dstv[ec]; s2=srcv[ec]; } else { d2=ec-E; s2=d2; }
    if (ed<E){ d3=dstv[ed]; s3=srcv[ed]; } else { d3=ed-E; s3=d3; }
    int r0=d0-lo, r1=d1-lo, r2=d2-lo, r3=d3-lo;
    if (r0>=0 && r0<HBINS){
      int base0 = rowptr[d0] + bpre[d0>>10] + (int)pb[d0];
      unsigned int o0 = atomicAdd(&cur[r0>>1], (r0&1)?65536u:1u);
      csr_src[base0 + ((r0&1)?(int)(o0>>16):(int)(o0&0xffff))] = s0;
    }
    if (r1>=0 && r1<HBINS){
      int base1 = rowptr[d1] + bpre[d1>>10] + (int)pb[d1];
      unsigned int o1 = atomicAdd(&cur[r1>>1], (r1&1)?65536u:1u);
      csr_src[base1 + ((r1&1)?(int)(o1>>16):(int)(o1&0xffff))] = s1;
    }
    if (r2>=0 && r2<HBINS){
      int base2 = rowptr[d2] + bpre[d2>>10] + (int)pb[d2];
      unsigned int o2 = atomicAdd(&cur[r2>>1], (r2&1)?65536u:1u);
      csr_src[base2 + ((r2&1)?(int)(o2>>16):(int)(o2&0xffff))] = s2;
    }
    if (r3>=0 && r3<HBINS){
      int base3 = rowptr[d3] + bpre[d3>>10] + (int)pb[d3];
      unsigned int o3 = atomicAdd(&cur[r3>>1], (r3&1)?65536u:1u);
      csr_src[base3 + ((r3&1)?(int)(o3>>16):(int)(o3&0xffff))] = s3;
    }
  }
  for (; e < e1; e += 256){
    int d,s;
    if (e<E){ d=dstv[e]; s=srcv[e]; } else { d=e-E; s=d; }
    int r = d - lo;
    if (r>=0 && r<HBINS){
      int base = rowptr[d] + bpre[d>>10] + (int)pb[d];
      unsigned int o = atomicAdd(&cur[r>>1], (r&1)?65536u:1u);
      csr_src[base + ((r&1)?(int)(o>>16):(int)(o&0xffff))] = s;
    }
  }
}

// ---------------- K4: Layer-1 aggregation (wave/dst, x8/x4/x1 unroll) ----------------
__global__ __launch_bounds__(256) void k_agg1(const __half* __restrict__ h1,
    const float* __restrict__ a_src1, const float* __restrict__ a_dst1,
    const int* __restrict__ rowfin, const int* __restrict__ csr_src,
    const float* __restrict__ bias1, _Float16* __restrict__ h2f, int N)
{
  int wave = (blockIdx.x*blockDim.x + threadIdx.x) >> 6;
  if (wave >= N) return;
  int lane = threadIdx.x & 63;
  int head = lane >> 3;
  float ad = a_dst1[(size_t)wave*8 + head];
  int beg = rowfin[wave], end = rowfin[wave+1];
  float4 acc = make_float4(0.f,0.f,0.f,0.f);
  float wsum = 0.f;
  int i = beg;
  for (; i+8 <= end; i+=8){
    int s[8]; float e[8]; uint2 p[8];
    #pragma unroll
    for (int j=0;j<8;++j) s[j]=csr_src[i+j];
    #pragma unroll
    for (int j=0;j<8;++j){
      e[j]=a_src1[(size_t)s[j]*8+head];
      p[j]=*(const uint2*)((const char*)h1 + (size_t)s[j]*512 + lane*8);
    }
    #pragma unroll
    for (int j=0;j<8;++j){
      float w=__expf(lrelu(e[j]+ad));
      wsum += w;
      const __half2* qq=(const __half2*)&p[j];
      float2 f0=__half22float2(qq[0]), f1=__half22float2(qq[1]);
      acc.x += w*f0.x; acc.y += w*f0.y; acc.z += w*f1.x; acc.w += w*f1.y;
    }
  }
  for (; i+4 <= end; i+=4){
    int s[4]; float e[4]; uint2 p[4];
    #pragma unroll
    for (int j=0;j<4;++j) s[j]=csr_src[i+j];
    #pragma unroll
    for (int j=0;j<4;++j){
      e[j]=a_src1[(size_t)s[j]*8+head];
      p[j]=*(const uint2*)((const char*)h1 + (size_t)s[j]*512 + lane*8);
    }
    #pragma unroll
    for (int j=0;j<4;++j){
      float w=__expf(lrelu(e[j]+ad));
      wsum += w;
      const __half2* qq=(const __half2*)&p[j];
      float2 f0=__half22float2(qq[0]), f1=__half22float2(qq[1]);
      acc.x += w*f0.x; acc.y += w*f0.y; acc.z += w*f1.x; acc.w += w*f1.y;
    }
  }
  for (; i<end; ++i){
    int s = csr_src[i];
    float w = __expf(lrelu(a_src1[(size_t)s*8+head] + ad));
    wsum += w;
    uint2 p = *(const uint2*)((const char*)h1 + (size_t)s*512 + lane*8);
    const __half2* qq=(const __half2*)&p;
    float2 f0=__half22float2(qq[0]), f1=__half22float2(qq[1]);
    acc.x += w*f0.x; acc.y += w*f0.y; acc.z += w*f1.x; acc.w += w*f1.y;
  }
  float dinv = 1.f/(wsum + 1e-16f);
  const float4 bv = *(const float4*)(bias1 + lane*4);
  float4 o;
  o.x = acc.x*dinv + bv.x;
  o.y = acc.y*dinv + bv.y;
  o.z = acc.z*dinv + bv.z;
  o.w = acc.w*dinv + bv.w;
  o.x = o.x > 0.f ? o.x : __expf(o.x)-1.f;
  o.y = o.y > 0.f ? o.y : __expf(o.y)-1.f;
  o.z = o.z > 0.f ? o.z : __expf(o.z)-1.f;
  o.w = o.w > 0.f ? o.w : __expf(o.w)-1.f;
  f16x4 ov = { (_Float16)o.x, (_Float16)o.y, (_Float16)o.z, (_Float16)o.w };
  *(f16x4*)(h2f + (size_t)wave*256 + lane*4) = ov;
}

// ---------------- K5: GEMM2 (MFMA): hb(fp16) = h2f @ W2, + a_src2/a_dst2 ----------------
__global__ __launch_bounds__(256) void k_gemm2(const _Float16* __restrict__ h2f,
    const _Float16* __restrict__ W2t, const float* __restrict__ as2, const float* __restrict__ ad2,
    _Float16* __restrict__ hbh, float* __restrict__ a_src2, float* __restrict__ a_dst2, int N)
{
  int t = threadIdx.x, wv = t>>6, lane = t&63;
  int col = lane&15, q = lane>>4;
  int n0 = blockIdx.x*64 + wv*16;
  int am = n0 + col; if (am > N-1) am = N-1;

  const _Float16* arow = h2f + (size_t)am*256 + q*8;
  const _Float16* brow = W2t + (size_t)col*256 + q*8;
  f32x4 acc = (f32x4){0.f,0.f,0.f,0.f};
  #pragma unroll
  for (int ks=0; ks<8; ++ks){
    f16x8 a = *(const f16x8*)(arow + ks*32);
    f16x8 b = *(const f16x8*)(brow + ks*32);
    acc = __builtin_amdgcn_mfma_f32_16x16x32_f16(a, b, acc, 0,0,0);
  }

  float vs = as2[col], vd = ad2[col];
  #pragma unroll
  for (int r=0; r<4; ++r){
    int n = n0 + q*4 + r;
    float v = acc[r];
    float pa = v*vs, pd = v*vd;
    #pragma unroll
    for (int msk=8; msk>=1; msk>>=1){ pa += __shfl_xor(pa,msk); pd += __shfl_xor(pd,msk); }
    if (n < N){
      hbh[(size_t)n*16 + col] = (_Float16)v;
      if (col==0){ a_src2[n] = pa; a_dst2[n] = pd; }
    }
  }
}

// ---------------- K6: Layer-2 aggregation: wave per dst, 4 edge-groups x 16 ch ----------------
__global__ __launch_bounds__(256) void k_agg2(const __half* __restrict__ hbh,
    const float* __restrict__ a_src2, const float* __restrict__ a_dst2,
    const int* __restrict__ rowfin, const int* __restrict__ csr_src,
    const float* __restrict__ bias2, float* __restrict__ out, int N)
{
  int wave = (blockIdx.x*blockDim.x + threadIdx.x) >> 6;
  if (wave >= N) return;
  int lane = threadIdx.x & 63;
  int eg   = lane >> 4;
  int ch   = lane & 15;
  float ad = a_dst2[wave];
  int beg = rowfin[wave], end = rowfin[wave+1];
  float acc = 0.f, wsum = 0.f;
  int i = beg + eg;
  for (; i+4 < end; i+=8){
    int s0 = csr_src[i], s1 = csr_src[i+4];
    float e0 = a_src2[s0], e1 = a_src2[s1];
    float h0 = __half2float(hbh[(size_t)s0*16 + ch]);
    float h1v = __half2float(hbh[(size_t)s1*16 + ch]);
    float w0 = __expf(lrelu(e0 + ad)), w1 = __expf(lrelu(e1 + ad));
    wsum += w0 + w1;
    acc += w0*h0 + w1*h1v;
  }
  for (; i<end; i+=4){
    int s = csr_src[i];
    float w = __expf(lrelu(a_src2[s] + ad));
    wsum += w;
    acc += w * __half2float(hbh[(size_t)s*16 + ch]);
  }
  acc  += __shfl_xor(acc, 16);  acc  += __shfl_xor(acc, 32);
  wsum += __shfl_xor(wsum, 16); wsum += __shfl_xor(wsum, 32);
  if (eg == 0)
    out[(size_t)wave*16 + ch] = acc/(wsum + 1e-16f) + bias2[ch];
}

extern "C" void kernel_launch(void* const* d_in, const int* in_sizes, int n_in,
                              void* d_out, int out_size, void* d_ws, size_t ws_size,
                              hipStream_t stream)
{
  const float* x   = (const float*)d_in[0];
  const int*   ei  = (const int*)  d_in[1];
  const float* W1  = (const float*)d_in[2];
  const float* as1 = (const float*)d_in[3];
  const float* ad1 = (const float*)d_in[4];
  const float* b1  = (const float*)d_in[5];
  const float* W2  = (const float*)d_in[6];
  const float* as2 = (const float*)d_in[7];
  const float* ad2 = (const float*)d_in[8];
  const float* b2  = (const float*)d_in[9];
  float* out = (float*)d_out;

  const int N    = in_sizes[0] / 128;       // 50000
  const int E    = in_sizes[1] / 2;         // 800000
  const int Etot = E + N;
  const int* srcv = ei;
  const int* dstv = ei + E;
  const int chunk = (Etot + NC - 1) / NC;   // 6641 < 65536 (u16-field safe)
  const int SB    = (N + 1023) / 1024;      // 49 scan blocks
  const int TN    = (N + 63) / 64;          // 782 gemm1 tiles

  char* p = (char*)d_ws;
  auto alloc = [&](size_t bytes)->void* {
    void* r = (void*)p;
    p += (bytes + 255) & ~((size_t)255);
    return r;
  };
  _Float16* h1   = (_Float16*)alloc((size_t)N*256*sizeof(_Float16));   // node-major [N][256]
  _Float16* W1t  = (_Float16*)alloc((size_t)256*128*sizeof(_Float16));
  _Float16* h2f  = (_Float16*)alloc((size_t)N*256*sizeof(_Float16));
  _Float16* W2t  = (_Float16*)alloc((size_t)16*256*sizeof(_Float16));
  _Float16* hbh  = (_Float16*)alloc((size_t)N*16*sizeof(_Float16));
  float* a_src1  = (float*)alloc((size_t)N*8*sizeof(float));
  float* a_dst1  = (float*)alloc((size_t)N*8*sizeof(float));
  float* a_src2  = (float*)alloc((size_t)N*sizeof(float));
  float* a_dst2  = (float*)alloc((size_t)N*sizeof(float));
  int*   rowptr  = (int*)alloc((size_t)(N+1)*sizeof(int));
  int*   rowfin  = (int*)alloc((size_t)(N+1)*sizeof(int));
  int*   bsum    = (int*)alloc(256*sizeof(int));
  unsigned int* partial = (unsigned int*)alloc((size_t)NC*HBINS*sizeof(unsigned int)); // u16[NC][50000]
  int*   csr_src = (int*)alloc((size_t)Etot*sizeof(int));

  // K1: histogram (chunk x half, 256 blocks) + weight prep
  k_histW<<<dim3(NBK+129), dim3(256), 0, stream>>>(dstv, partial, E, Etot, chunk,
                                                   W1, W1t, W2, W2t);
  // K2: scanAB (blocks 0..SB-1) + gemm1 (blocks SB..SB+TN-1) -- independent halves
  k_g1scan<<<dim3(SB + TN), dim3(256), 0, stream>>>(x, W1t, as1, ad1, h1,
      a_src1, a_dst1, (unsigned long long*)partial, rowptr, bsum, N, SB);
  // K3: scatter + rowfin finalize
  k_scatter3<<<dim3(NBK), dim3(256), 0, stream>>>(srcv, dstv, rowptr,
      (const unsigned short*)partial, bsum, csr_src, rowfin, E, Etot, chunk, SB, N);
  // K4: agg1
  k_agg1<<<dim3((N + 3)/4), dim3(256), 0, stream>>>((const __half*)h1, a_src1, a_dst1,
      rowfin, csr_src, b1, h2f, N);
  // K5: gemm2 (fp16 hb)
  k_gemm2<<<dim3((N + 63)/64), dim3(256), 0, stream>>>(h2f, W2t, as2, ad2, hbh, a_src2, a_dst2, N);
  // K6: agg2
  k_agg2<<<dim3((N + 3)/4), dim3(256), 0, stream>>>((const __half*)hbh, a_src2, a_dst2,
      rowfin, csr_src, b2, out, N);
}